// Round 2
// baseline (591.497 us; speedup 1.0000x reference)
//
#include <hip/hip_runtime.h>
#include <hip/hip_bf16.h>
#include <math.h>

typedef unsigned short u16;
typedef __attribute__((ext_vector_type(8))) short s16x8;
typedef __attribute__((ext_vector_type(4))) float f32x4;
typedef __attribute__((ext_vector_type(4))) unsigned short u16x4;

__device__ __forceinline__ u16 f2bf(float f) {
  union { float f; unsigned u; } v; v.f = f;
  unsigned r = (v.u + 0x7FFFu + ((v.u >> 16) & 1u)) >> 16;
  return (u16)r;
}

__device__ __forceinline__ void gload16(const void* g, void* l) {
  __builtin_amdgcn_global_load_lds((const __attribute__((address_space(1))) unsigned int*)g,
                                   (__attribute__((address_space(3))) unsigned int*)l, 16, 0, 0);
}

// ---------------- elementwise prep ----------------

__global__ __launch_bounds__(256) void cvt_weights(
    const float* __restrict__ wq, const float* __restrict__ wk, const float* __restrict__ wv,
    const float* __restrict__ wo, const float* __restrict__ wf,
    u16* __restrict__ wqkv, u16* __restrict__ wobf, u16* __restrict__ wfbf)
{
  int i = blockIdx.x * 256 + threadIdx.x;   // 5 * 262144 float4 units
  int which = i >> 18;
  int idx = i & 262143;
  const float* src = which==0 ? wq : which==1 ? wk : which==2 ? wv : which==3 ? wo : wf;
  float4 v = ((const float4*)src)[idx];
  u16x4 o = { f2bf(v.x), f2bf(v.y), f2bf(v.z), f2bf(v.w) };
  u16* dst = which < 3 ? (wqkv + (size_t)which*1048576) : (which==3 ? wobf : wfbf);
  ((u16x4*)dst)[idx] = o;
}

// M[b*1664 + s] = rows of [x(1024); h_a(64); p(64); h_t(512)] per batch, bf16
__global__ __launch_bounds__(256) void build_m(
    const float* __restrict__ x, const float* __restrict__ ht,
    const float* __restrict__ ha, const float* __restrict__ p,
    u16* __restrict__ M)
{
  int row = blockIdx.x; int t = threadIdx.x;
  int b = row / 1664, s = row % 1664;
  const float* src;
  if (s < 1024)      src = x  + (size_t)(b*1024 + s)*1024;
  else if (s < 1088) src = ha + (size_t)(b*64 + (s-1024))*1024;
  else if (s < 1152) src = p  + (size_t)(b*64 + (s-1088))*1024;
  else               src = ht + (size_t)(b*512 + (s-1152))*1024;
  float4 v = ((const float4*)src)[t];
  u16x4 o = { f2bf(v.x), f2bf(v.y), f2bf(v.z), f2bf(v.w) };
  ((u16x4*)(M + (size_t)row*1024))[t] = o;
}

// ---------------- GEMM: C[M,N] = A[M,K] @ B[N,K]^T, m97-style 128x128 tile ----------------
// EPI 0: QKV fused epilogue. EPI 1: +bo +x -> fp32 y. EPI 2: +bf, relu -> fp32 out.

template<int EPI>
__global__ __launch_bounds__(256) void gemm_bt(
    const u16* __restrict__ A, const u16* __restrict__ Bw, int K,
    const float* __restrict__ bias0, const float* __restrict__ bias1, const float* __restrict__ bias2,
    const void* p0, void* p1, void* p2, void* p3)
{
  __shared__ __align__(16) u16 As[128*32];
  __shared__ __align__(16) u16 Bs[128*32];
  const int tid = threadIdx.x;
  const int l = tid & 63;
  const int w = tid >> 6;
  const int m0 = blockIdx.x * 128;
  const int n0 = blockIdx.y * 128;

  if constexpr (EPI == 0) {
    // Q region only needed for token rows (s<1024); whole 128-tile is single-region.
    if (n0 < 1024 && (m0 % 1664) >= 1024) return;
  }

  const int wr = w >> 1, wc = w & 1;
  const int l15 = l & 15, lg = l >> 4;

  f32x4 acc[4][4];
  #pragma unroll
  for (int i=0;i<4;++i)
    #pragma unroll
    for (int j=0;j<4;++j) acc[i][j] = (f32x4){0,0,0,0};

  const int kiters = K >> 5;
  for (int kt = 0; kt < kiters; ++kt) {
    __syncthreads();
    #pragma unroll
    for (int c = 0; c < 2; ++c) {
      const int rbase = w*32 + c*16;
      const int rl = rbase + (l >> 2);
      const int kb = kt*32 + (l & 3)*8;
      gload16(A  + (size_t)(m0 + rl)*K + kb, (void*)(As + rbase*32));
      gload16(Bw + (size_t)(n0 + rl)*K + kb, (void*)(Bs + rbase*32));
    }
    __syncthreads();
    s16x8 av[4];
    #pragma unroll
    for (int mi=0;mi<4;++mi)
      av[mi] = *(const s16x8*)(As + (wr*64 + mi*16 + l15)*32 + lg*8);
    #pragma unroll
    for (int ni=0;ni<4;++ni) {
      s16x8 bv = *(const s16x8*)(Bs + (wc*64 + ni*16 + l15)*32 + lg*8);
      #pragma unroll
      for (int mi=0;mi<4;++mi)
        acc[mi][ni] = __builtin_amdgcn_mfma_f32_16x16x32_bf16(av[mi], bv, acc[mi][ni], 0,0,0);
    }
  }

  float ratio = 0.f;
  if constexpr (EPI == 0) ratio = tanhf(((const float*)p0)[0]);

  #pragma unroll
  for (int mi=0;mi<4;++mi) {
    #pragma unroll
    for (int ni=0;ni<4;++ni) {
      #pragma unroll
      for (int r=0;r<4;++r) {
        const int row = m0 + wr*64 + mi*16 + lg*4 + r;
        const int col = n0 + wc*64 + ni*16 + l15;
        if constexpr (EPI == 0) {
          const int b = row / 1664, s = row % 1664;
          if (col < 1024) {
            float v = acc[mi][ni][r] + bias0[col];
            if (s < 1024)
              ((u16*)p1)[(size_t)(b*1024 + s)*1024 + col] = f2bf(v * 0.08838834764831845f);
          } else if (col < 2048) {
            float v = acc[mi][ni][r] + bias1[col-1024];
            if (s >= 1152) v *= ratio;
            ((u16*)p2)[(size_t)row*1024 + (col-1024)] = f2bf(v);
          } else {
            float v = acc[mi][ni][r] + bias2[col-2048];
            ((u16*)p3)[(size_t)row*1024 + (col-2048)] = f2bf(v);
          }
        } else if constexpr (EPI == 1) {
          float v = acc[mi][ni][r] + bias0[col] + ((const float*)p0)[(size_t)row*1024 + col];
          ((float*)p1)[(size_t)row*1024 + col] = v;
        } else {
          float v = acc[mi][ni][r] + bias0[col];
          ((float*)p1)[(size_t)row*1024 + col] = fmaxf(v, 0.f);
        }
      }
    }
  }
}

// ---------------- flash attention over S=1664, D=128 ----------------
// grid: (B*H)*16 blocks, 256 thr = 4 waves, each wave owns 16 q-rows; KV tile = 64.

__global__ __launch_bounds__(256) void flash_attn(
    const u16* __restrict__ Q, const u16* __restrict__ Kb, const u16* __restrict__ Vb,
    u16* __restrict__ O)
{
  __shared__ __align__(16) u16 Kl[64*128];   // [s][d], 16B-chunk XOR-swizzled by (s&7)
  __shared__ __align__(16) u16 Vt[128*64];   // [d][s], chunk XOR-swizzled by (d&7)
  __shared__ __align__(16) u16 Pl[4][16*64]; // per-wave P, chunk XOR-swizzled by (row&7)

  const int tid = threadIdx.x;
  const int l = tid & 63;
  const int w = tid >> 6;
  const int bh = blockIdx.x >> 4;
  const int qt = blockIdx.x & 15;
  const int b = bh >> 3, h = bh & 7;
  const int colh = h * 128;
  const int l15 = l & 15, lg = l >> 4;

  // Q fragments (rows w*16 + (l&15), K=128 in 4 chunks of 32)
  s16x8 qf[4];
  const size_t qrow0 = (size_t)(b*1024 + qt*64 + w*16 + l15)*1024 + colh;
  #pragma unroll
  for (int kc=0;kc<4;++kc) qf[kc] = *(const s16x8*)(Q + qrow0 + kc*32 + lg*8);

  f32x4 sacc[4];
  f32x4 oacc[8];
  #pragma unroll
  for (int i=0;i<8;++i) oacc[i] = (f32x4){0,0,0,0};
  float mprev[4], lsum[4];
  #pragma unroll
  for (int r=0;r<4;++r) { mprev[r] = -INFINITY; lsum[r] = 0.f; }

  const size_t kvbase = (size_t)b*1664*1024 + colh;

  for (int st=0; st<26; ++st) {
    const int s0 = st*64;
    __syncthreads();
    // stage K tile [64][128]: global source pre-swizzled so linear LDS dest holds swizzled layout
    #pragma unroll
    for (int c=0;c<4;++c) {
      const int rloc = w*16 + c*4 + lg;
      const int chk = l15 ^ (rloc & 7);
      gload16(Kb + kvbase + (size_t)(s0 + rloc)*1024 + chk*8, (void*)(Kl + (w*16 + c*4)*128));
    }
    // stage V transposed: Vt[d][s]
    #pragma unroll
    for (int half=0; half<2; ++half) {
      const int sb = tid + half*256;
      const int sbd = sb & 31, sbs = sb >> 5;
      u16x4 vv[4];
      #pragma unroll
      for (int i=0;i<4;++i)
        vv[i] = *(const u16x4*)(Vb + kvbase + (size_t)(s0 + sbs*4 + i)*1024 + sbd*4);
      #pragma unroll
      for (int j=0;j<4;++j) {
        const int d = sbd*4 + j;
        u16x4 ov = { vv[0][j], vv[1][j], vv[2][j], vv[3][j] };
        *(u16x4*)(Vt + d*64 + (((sbs>>1) ^ (d&7))<<3) + (sbs&1)*4) = ov;
      }
    }
    __syncthreads();

    // S = Q K^T  (16 x 64 per wave)
    #pragma unroll
    for (int nt=0;nt<4;++nt) {
      f32x4 s = {0,0,0,0};
      const int srow = nt*16 + l15;
      #pragma unroll
      for (int kc=0;kc<4;++kc) {
        s16x8 kf = *(const s16x8*)(Kl + srow*128 + (((kc*4 + lg) ^ (srow & 7)) << 3));
        s = __builtin_amdgcn_mfma_f32_16x16x32_bf16(qf[kc], kf, s, 0,0,0);
      }
      sacc[nt] = s;
    }

    // online softmax; lane's rows are lg*4+r, row-reduce across 16 lanes
    #pragma unroll
    for (int r=0;r<4;++r) {
      float rm = fmaxf(fmaxf(sacc[0][r], sacc[1][r]), fmaxf(sacc[2][r], sacc[3][r]));
      #pragma unroll
      for (int off=1; off<16; off<<=1) rm = fmaxf(rm, __shfl_xor(rm, off));
      const float mnew = fmaxf(mprev[r], rm);
      const float alpha = __expf(mprev[r] - mnew);
      float psum = 0.f;
      #pragma unroll
      for (int nt=0;nt<4;++nt) {
        float pv = __expf(sacc[nt][r] - mnew);
        sacc[nt][r] = pv;
        psum += pv;
      }
      #pragma unroll
      for (int off=1; off<16; off<<=1) psum += __shfl_xor(psum, off);
      lsum[r] = lsum[r]*alpha + psum;
      mprev[r] = mnew;
      #pragma unroll
      for (int nt2=0; nt2<8; ++nt2) oacc[nt2][r] *= alpha;
    }

    // P -> LDS (bf16, swizzled); wave-private, in-order LDS, no barrier needed
    #pragma unroll
    for (int nt=0;nt<4;++nt) {
      const int col = nt*16 + l15;
      #pragma unroll
      for (int r=0;r<4;++r) {
        const int row = lg*4 + r;
        Pl[w][row*64 + (((col>>3) ^ (row&7))<<3) + (col&7)] = f2bf(sacc[nt][r]);
      }
    }

    // O += P V
    s16x8 ap[2];
    #pragma unroll
    for (int kc2=0; kc2<2; ++kc2)
      ap[kc2] = *(const s16x8*)(&Pl[w][l15*64 + (((kc2*4 + lg) ^ (l15 & 7)) << 3)]);
    #pragma unroll
    for (int nt2=0; nt2<8; ++nt2) {
      const int d = nt2*16 + l15;
      #pragma unroll
      for (int kc2=0; kc2<2; ++kc2) {
        s16x8 vf = *(const s16x8*)(Vt + d*64 + (((kc2*4 + lg) ^ (d & 7)) << 3));
        oacc[nt2] = __builtin_amdgcn_mfma_f32_16x16x32_bf16(ap[kc2], vf, oacc[nt2], 0,0,0);
      }
    }
  }

  float rinv[4];
  #pragma unroll
  for (int r=0;r<4;++r) rinv[r] = 1.f / lsum[r];
  const size_t orow0 = (size_t)(b*1024 + qt*64 + w*16);
  #pragma unroll
  for (int nt2=0; nt2<8; ++nt2)
    #pragma unroll
    for (int r=0;r<4;++r)
      O[(orow0 + lg*4 + r)*1024 + colh + nt2*16 + l15] = f2bf(oacc[nt2][r] * rinv[r]);
}

// ---------------- LayerNorm (block per row of 1024) ----------------

__global__ __launch_bounds__(256) void ln_kernel(
    const float* __restrict__ y, const float* __restrict__ g, const float* __restrict__ bb,
    u16* __restrict__ out)
{
  const int row = blockIdx.x, t = threadIdx.x;
  float4 v = ((const float4*)y)[row*256 + t];
  float s  = v.x + v.y + v.z + v.w;
  float s2 = v.x*v.x + v.y*v.y + v.z*v.z + v.w*v.w;
  #pragma unroll
  for (int off=1; off<64; off<<=1) { s += __shfl_xor(s, off); s2 += __shfl_xor(s2, off); }
  __shared__ float ps[4], ps2[4];
  const int w = t >> 6;
  if ((t & 63) == 0) { ps[w] = s; ps2[w] = s2; }
  __syncthreads();
  s  = ps[0] + ps[1] + ps[2] + ps[3];
  s2 = ps2[0] + ps2[1] + ps2[2] + ps2[3];
  const float mu = s * (1.f/1024.f);
  const float var = s2 * (1.f/1024.f) - mu*mu;
  const float rs = rsqrtf(var + 1e-5f);
  float4 gg = ((const float4*)g)[t];
  float4 bv = ((const float4*)bb)[t];
  u16x4 o = { f2bf((v.x-mu)*rs*gg.x + bv.x),
              f2bf((v.y-mu)*rs*gg.y + bv.y),
              f2bf((v.z-mu)*rs*gg.z + bv.z),
              f2bf((v.w-mu)*rs*gg.w + bv.w) };
  ((u16x4*)out)[row*256 + t] = o;
}

// ---------------- launcher ----------------

extern "C" void kernel_launch(void* const* d_in, const int* in_sizes, int n_in,
                              void* d_out, int out_size, void* d_ws, size_t ws_size,
                              hipStream_t stream)
{
  (void)in_sizes; (void)n_in; (void)out_size; (void)ws_size;
  const float* x   = (const float*)d_in[0];
  const float* ht  = (const float*)d_in[1];
  const float* ha  = (const float*)d_in[2];
  const float* pp  = (const float*)d_in[3];
  const float* Wq  = (const float*)d_in[4];
  const float* bq  = (const float*)d_in[5];
  const float* Wk  = (const float*)d_in[6];
  const float* bk  = (const float*)d_in[7];
  const float* Wv  = (const float*)d_in[8];
  const float* bv  = (const float*)d_in[9];
  const float* Wo  = (const float*)d_in[10];
  const float* bo  = (const float*)d_in[11];
  const float* gat = (const float*)d_in[12];
  const float* lng = (const float*)d_in[13];
  const float* lnb = (const float*)d_in[14];
  const float* Wf  = (const float*)d_in[15];
  const float* bfp = (const float*)d_in[16];
  float* out = (float*)d_out;

  char* ws = (char*)d_ws;
  size_t off = 0;
  auto alloc = [&](size_t bytes) { void* r = ws + off; off += (bytes + 255) & ~255ull; return r; };
  u16* M    = (u16*)alloc(13312ull*1024*2);  // 27.26 MB (dead after QKV gemm)
  u16* Wqkv = (u16*)alloc(3072ull*1024*2);   //  6.29 MB (dead after QKV gemm)
  u16* Wobf = (u16*)alloc(1024ull*1024*2);
  u16* Wfbf = (u16*)alloc(1024ull*1024*2);
  u16* Qb   = (u16*)alloc(8192ull*1024*2);   // dead after flash
  u16* Kb2  = (u16*)alloc(13312ull*1024*2);
  u16* Vb2  = (u16*)alloc(13312ull*1024*2);
  u16* Ab   = (u16*)alloc(8192ull*1024*2);
  float* Y  = (float*)M;                     // 32 MB overlay onto M+Wqkv (exact fit)
  u16* Ln   = Qb;                            // overlay onto Qb

  hipLaunchKernelGGL(cvt_weights, dim3(5120), dim3(256), 0, stream,
                     Wq, Wk, Wv, Wo, Wf, Wqkv, Wobf, Wfbf);
  hipLaunchKernelGGL(build_m, dim3(13312), dim3(256), 0, stream, x, ht, ha, pp, M);
  hipLaunchKernelGGL((gemm_bt<0>), dim3(104, 24), dim3(256), 0, stream,
                     M, Wqkv, 1024, bq, bk, bv,
                     (const void*)gat, (void*)Qb, (void*)Kb2, (void*)Vb2);
  hipLaunchKernelGGL(flash_attn, dim3(1024), dim3(256), 0, stream, Qb, Kb2, Vb2, Ab);
  hipLaunchKernelGGL((gemm_bt<1>), dim3(64, 8), dim3(256), 0, stream,
                     Ab, Wobf, 1024, bo, nullptr, nullptr,
                     (const void*)x, (void*)Y, nullptr, nullptr);
  hipLaunchKernelGGL(ln_kernel, dim3(8192), dim3(256), 0, stream, Y, lng, lnb, Ln);
  hipLaunchKernelGGL((gemm_bt<2>), dim3(64, 8), dim3(256), 0, stream,
                     Ln, Wfbf, 1024, bfp, nullptr, nullptr,
                     nullptr, (void*)out, nullptr, nullptr);
}

// Round 3
// 489.583 us; speedup vs baseline: 1.2082x; 1.2082x over previous
//
#include <hip/hip_runtime.h>
#include <hip/hip_bf16.h>
#include <math.h>

typedef unsigned short u16;
typedef __attribute__((ext_vector_type(8))) short s16x8;
typedef __attribute__((ext_vector_type(4))) float f32x4;
typedef __attribute__((ext_vector_type(16))) float f32x16;
typedef __attribute__((ext_vector_type(4))) unsigned short u16x4;

__device__ __forceinline__ u16 f2bf(float f) {
  union { float f; unsigned u; } v; v.f = f;
  unsigned r = (v.u + 0x7FFFu + ((v.u >> 16) & 1u)) >> 16;
  return (u16)r;
}

__device__ __forceinline__ void gload16(const void* g, void* l) {
  __builtin_amdgcn_global_load_lds((const __attribute__((address_space(1))) unsigned int*)g,
                                   (__attribute__((address_space(3))) unsigned int*)l, 16, 0, 0);
}

__device__ __forceinline__ unsigned cvt_pk_bf16(float a, float b) {
  unsigned r;
  asm("v_cvt_pk_bf16_f32 %0, %1, %2" : "=v"(r) : "v"(a), "v"(b));
  return r;
}

// ---------------- elementwise prep ----------------

__global__ __launch_bounds__(256) void cvt_weights(
    const float* __restrict__ wq, const float* __restrict__ wk, const float* __restrict__ wv,
    const float* __restrict__ wo, const float* __restrict__ wf,
    u16* __restrict__ wqkv, u16* __restrict__ wobf, u16* __restrict__ wfbf)
{
  int i = blockIdx.x * 256 + threadIdx.x;   // 5 * 262144 float4 units
  int which = i >> 18;
  int idx = i & 262143;
  const float* src = which==0 ? wq : which==1 ? wk : which==2 ? wv : which==3 ? wo : wf;
  float4 v = ((const float4*)src)[idx];
  u16x4 o = { f2bf(v.x), f2bf(v.y), f2bf(v.z), f2bf(v.w) };
  u16* dst = which < 3 ? (wqkv + (size_t)which*1048576) : (which==3 ? wobf : wfbf);
  ((u16x4*)dst)[idx] = o;
}

// M[b*1664 + s] = rows of [x(1024); h_a(64); p(64); h_t(512)] per batch, bf16
__global__ __launch_bounds__(256) void build_m(
    const float* __restrict__ x, const float* __restrict__ ht,
    const float* __restrict__ ha, const float* __restrict__ p,
    u16* __restrict__ M)
{
  int row = blockIdx.x; int t = threadIdx.x;
  int b = row / 1664, s = row % 1664;
  const float* src;
  if (s < 1024)      src = x  + (size_t)(b*1024 + s)*1024;
  else if (s < 1088) src = ha + (size_t)(b*64 + (s-1024))*1024;
  else if (s < 1152) src = p  + (size_t)(b*64 + (s-1088))*1024;
  else               src = ht + (size_t)(b*512 + (s-1152))*1024;
  float4 v = ((const float4*)src)[t];
  u16x4 o = { f2bf(v.x), f2bf(v.y), f2bf(v.z), f2bf(v.w) };
  ((u16x4*)(M + (size_t)row*1024))[t] = o;
}

// ---------------- GEMM: C[M,N] = A[M,K] @ B[N,K]^T, m97-style 128x128 tile ----------------
// EPI 0: QKV fused epilogue. EPI 1: +bo +x -> fp32 y. EPI 2: +bf, relu -> fp32 out.

template<int EPI>
__global__ __launch_bounds__(256) void gemm_bt(
    const u16* __restrict__ A, const u16* __restrict__ Bw, int K,
    const float* __restrict__ bias0, const float* __restrict__ bias1, const float* __restrict__ bias2,
    const void* p0, void* p1, void* p2, void* p3)
{
  __shared__ __align__(16) u16 As[128*32];
  __shared__ __align__(16) u16 Bs[128*32];
  const int tid = threadIdx.x;
  const int l = tid & 63;
  const int w = tid >> 6;
  const int m0 = blockIdx.x * 128;
  const int n0 = blockIdx.y * 128;

  if constexpr (EPI == 0) {
    if (n0 < 1024 && (m0 % 1664) >= 1024) return;
  }

  const int wr = w >> 1, wc = w & 1;
  const int l15 = l & 15, lg = l >> 4;

  f32x4 acc[4][4];
  #pragma unroll
  for (int i=0;i<4;++i)
    #pragma unroll
    for (int j=0;j<4;++j) acc[i][j] = (f32x4){0,0,0,0};

  const int kiters = K >> 5;
  for (int kt = 0; kt < kiters; ++kt) {
    __syncthreads();
    #pragma unroll
    for (int c = 0; c < 2; ++c) {
      const int rbase = w*32 + c*16;
      const int rl = rbase + (l >> 2);
      const int kb = kt*32 + (l & 3)*8;
      gload16(A  + (size_t)(m0 + rl)*K + kb, (void*)(As + rbase*32));
      gload16(Bw + (size_t)(n0 + rl)*K + kb, (void*)(Bs + rbase*32));
    }
    __syncthreads();
    s16x8 av[4];
    #pragma unroll
    for (int mi=0;mi<4;++mi)
      av[mi] = *(const s16x8*)(As + (wr*64 + mi*16 + l15)*32 + lg*8);
    #pragma unroll
    for (int ni=0;ni<4;++ni) {
      s16x8 bv = *(const s16x8*)(Bs + (wc*64 + ni*16 + l15)*32 + lg*8);
      #pragma unroll
      for (int mi=0;mi<4;++mi)
        acc[mi][ni] = __builtin_amdgcn_mfma_f32_16x16x32_bf16(av[mi], bv, acc[mi][ni], 0,0,0);
    }
  }

  float ratio = 0.f;
  if constexpr (EPI == 0) ratio = tanhf(((const float*)p0)[0]);

  #pragma unroll
  for (int mi=0;mi<4;++mi) {
    #pragma unroll
    for (int ni=0;ni<4;++ni) {
      #pragma unroll
      for (int r=0;r<4;++r) {
        const int row = m0 + wr*64 + mi*16 + lg*4 + r;
        const int col = n0 + wc*64 + ni*16 + l15;
        if constexpr (EPI == 0) {
          const int b = row / 1664, s = row % 1664;
          if (col < 1024) {
            float v = acc[mi][ni][r] + bias0[col];
            if (s < 1024)
              ((u16*)p1)[(size_t)(b*1024 + s)*1024 + col] = f2bf(v * 0.08838834764831845f);
          } else if (col < 2048) {
            float v = acc[mi][ni][r] + bias1[col-1024];
            if (s >= 1152) v *= ratio;
            ((u16*)p2)[(size_t)row*1024 + (col-1024)] = f2bf(v);
          } else {
            float v = acc[mi][ni][r] + bias2[col-2048];
            ((u16*)p3)[(size_t)row*1024 + (col-2048)] = f2bf(v);
          }
        } else if constexpr (EPI == 1) {
          float v = acc[mi][ni][r] + bias0[col] + ((const float*)p0)[(size_t)row*1024 + col];
          ((float*)p1)[(size_t)row*1024 + col] = v;
        } else {
          float v = acc[mi][ni][r] + bias0[col];
          ((float*)p1)[(size_t)row*1024 + col] = fmaxf(v, 0.f);
        }
      }
    }
  }
}

// ---------------- V transpose: Vt[b][c=1024][s=1664] = V[b][s][c] ----------------

__global__ __launch_bounds__(256) void vtrans(
    const u16* __restrict__ V, u16* __restrict__ Vt)
{
  __shared__ u16 Ls[64][68];
  const int st = blockIdx.x, dt = blockIdx.y, b = blockIdx.z;
  const int t = threadIdx.x;
  const int rq = t >> 4, c4 = t & 15;
  #pragma unroll
  for (int i=0;i<4;++i) {
    const int r = i*16 + rq;
    u16x4 v = *(const u16x4*)(V + ((size_t)(b*1664 + st*64 + r))*1024 + dt*64 + c4*4);
    Ls[r][c4*4+0] = v[0]; Ls[r][c4*4+1] = v[1]; Ls[r][c4*4+2] = v[2]; Ls[r][c4*4+3] = v[3];
  }
  __syncthreads();
  #pragma unroll
  for (int i=0;i<4;++i) {
    const int dr = i*16 + rq;
    u16x4 ov = { Ls[c4*4+0][dr], Ls[c4*4+1][dr], Ls[c4*4+2][dr], Ls[c4*4+3][dr] };
    *(u16x4*)(Vt + ((size_t)(b*1024 + dt*64 + dr))*1664 + st*64 + c4*4) = ov;
  }
}

// ---------------- flash attention, 32x32 swapped-QK, S=1664, D=128 ----------------
// grid 512 blocks (bh = blk&63, qt = blk>>6), 256 thr = 4 waves x 32 q-rows; KVB=64, dbuf.

__global__ __launch_bounds__(256, 2) void flash_attn(
    const u16* __restrict__ Q, const u16* __restrict__ Kb, const u16* __restrict__ Vtg,
    u16* __restrict__ O)
{
  __shared__ __align__(16) u16 Kl[2][64*128];   // [s][16 chunks of 8 u16], chunk low3 ^= s&7
  __shared__ __align__(16) u16 Vl[2][128*64];   // [d][8 chunks of 8 u16], chunk ^= d&7

  const int tid = threadIdx.x;
  const int l = tid & 63;
  const int w = tid >> 6;
  const int l31 = l & 31;
  const int hi = l >> 5;
  const int bh = blockIdx.x & 63;
  const int qt = blockIdx.x >> 6;
  const int b = bh >> 3, h = bh & 7;
  const int colh = h * 128;
  const int q0 = qt*128 + w*32;

  // Q fragments in registers: lane l31 = q-row, k chunks of 16 (hi*8+e)
  s16x8 qf[8];
  {
    const size_t qrow = (size_t)(b*1024 + q0 + l31)*1024 + colh;
    #pragma unroll
    for (int kc=0;kc<8;++kc)
      qf[kc] = *(const s16x8*)(Q + qrow + kc*16 + hi*8);
  }

  f32x16 oacc[4];
  #pragma unroll
  for (int dt2=0;dt2<4;++dt2)
    #pragma unroll
    for (int i=0;i<16;++i) oacc[dt2][i] = 0.f;
  float m_run = -INFINITY, l_run = 0.f;

  const size_t kbase  = (size_t)(b*1664)*1024 + colh;
  const size_t vtbase = (size_t)(b*1024 + colh)*1664;

  // stage tile st into buffer nb
  auto stage = [&](int st, int nb) {
    const int s0 = st*64;
    #pragma unroll
    for (int i=0;i<4;++i) {
      const int e = i*256 + tid;
      const int sl = e >> 4, c = e & 15;
      const int g = (c & 8) | ((c ^ sl) & 7);
      gload16(Kb + kbase + (size_t)(s0 + sl)*1024 + g*8,
              (void*)(Kl[nb] + (i*256 + w*64)*8));
    }
    #pragma unroll
    for (int i=0;i<4;++i) {
      const int e = i*256 + tid;
      const int d = e >> 3, c3 = e & 7;
      const int g3 = (c3 ^ d) & 7;
      gload16(Vtg + vtbase + (size_t)d*1664 + s0 + g3*8,
              (void*)(Vl[nb] + (i*256 + w*64)*8));
    }
  };

  stage(0, 0);
  __syncthreads();
  int cur = 0;

  for (int st=0; st<26; ++st) {
    if (st + 1 < 26) stage(st + 1, cur ^ 1);

    // ---- S^T = K · Q^T : per stile, D[col=l31=q][row(reg,hi)=s'] ----
    f32x16 sacc[2];
    #pragma unroll
    for (int stile=0; stile<2; ++stile) {
      #pragma unroll
      for (int i=0;i<16;++i) sacc[stile][i] = 0.f;
      #pragma unroll
      for (int kc=0; kc<8; ++kc) {
        const int sl = stile*32 + l31;
        const int gc = kc*2 + hi;
        const int cl = (gc & 8) | ((gc ^ sl) & 7);
        s16x8 kf = *(const s16x8*)(Kl[cur] + sl*128 + cl*8);
        sacc[stile] = __builtin_amdgcn_mfma_f32_32x32x16_bf16(kf, qf[kc], sacc[stile], 0,0,0);
      }
    }

    // ---- online softmax: lane owns q = l31 ----
    float tm[8];
    #pragma unroll
    for (int i=0;i<8;++i)
      tm[i] = fmaxf(fmaxf(sacc[0][i], sacc[0][i+8]), fmaxf(sacc[1][i], sacc[1][i+8]));
    float pm = fmaxf(fmaxf(fmaxf(tm[0],tm[1]), fmaxf(tm[2],tm[3])),
                     fmaxf(fmaxf(tm[4],tm[5]), fmaxf(tm[6],tm[7])));
    pm = fmaxf(pm, __shfl_xor(pm, 32));

    if (__any(pm > m_run + 8.f)) {
      const float mnew = fmaxf(m_run, pm);
      const float alpha = __expf(m_run - mnew);
      m_run = mnew;
      l_run *= alpha;
      #pragma unroll
      for (int r=0;r<16;++r) {
        const int qr = (r&3) + 8*(r>>2) + 4*hi;
        const float ar = __shfl(alpha, qr);
        #pragma unroll
        for (int dt2=0;dt2<4;++dt2) oacc[dt2][r] *= ar;
      }
    }

    float ps = 0.f;
    #pragma unroll
    for (int stile=0; stile<2; ++stile)
      #pragma unroll
      for (int i=0;i<16;++i) {
        const float v = __expf(sacc[stile][i] - m_run);
        sacc[stile][i] = v;
        ps += v;
      }
    ps += __shfl_xor(ps, 32);
    l_run += ps;

    // ---- P (f32 regs) -> bf16 A-frags, in-register (cvt_pk + shfl_xor(32)) ----
    s16x8 pf[4];
    #pragma unroll
    for (int kc2=0; kc2<4; ++kc2) {
      const int stile = kc2 >> 1;
      const int rb = (kc2 & 1) * 8;
      const unsigned A = cvt_pk_bf16(sacc[stile][rb+0], sacc[stile][rb+1]);
      const unsigned B = cvt_pk_bf16(sacc[stile][rb+2], sacc[stile][rb+3]);
      const unsigned C = cvt_pk_bf16(sacc[stile][rb+4], sacc[stile][rb+5]);
      const unsigned D = cvt_pk_bf16(sacc[stile][rb+6], sacc[stile][rb+7]);
      const unsigned x1 = (unsigned)__shfl_xor((int)(hi ? A : C), 32);
      const unsigned x2 = (unsigned)__shfl_xor((int)(hi ? B : D), 32);
      union { unsigned u[4]; s16x8 v; } fr;
      fr.u[0] = hi ? x1 : A;
      fr.u[1] = hi ? x2 : B;
      fr.u[2] = hi ? C : x1;
      fr.u[3] = hi ? D : x2;
      pf[kc2] = fr.v;
    }

    // ---- O += P · V : D[col=l31=d][row(reg,hi)=q] ----
    #pragma unroll
    for (int dt2=0; dt2<4; ++dt2) {
      const int d = dt2*32 + l31;
      #pragma unroll
      for (int kc2=0; kc2<4; ++kc2) {
        const int g3 = kc2*2 + hi;
        const int cl3 = (g3 ^ d) & 7;
        s16x8 vf = *(const s16x8*)(Vl[cur] + d*64 + cl3*8);
        oacc[dt2] = __builtin_amdgcn_mfma_f32_32x32x16_bf16(pf[kc2], vf, oacc[dt2], 0,0,0);
      }
    }

    __syncthreads();
    cur ^= 1;
  }

  const float linv = 1.f / l_run;
  #pragma unroll
  for (int r=0;r<16;++r) {
    const int qr = (r&3) + 8*(r>>2) + 4*hi;
    const float lr = __shfl(linv, qr);
    const size_t row = (size_t)(b*1024 + q0 + qr)*1024 + colh;
    #pragma unroll
    for (int dt2=0;dt2<4;++dt2)
      O[row + dt2*32 + l31] = f2bf(oacc[dt2][r] * lr);
  }
}

// ---------------- LayerNorm (block per row of 1024) ----------------

__global__ __launch_bounds__(256) void ln_kernel(
    const float* __restrict__ y, const float* __restrict__ g, const float* __restrict__ bb,
    u16* __restrict__ out)
{
  const int row = blockIdx.x, t = threadIdx.x;
  float4 v = ((const float4*)y)[row*256 + t];
  float s  = v.x + v.y + v.z + v.w;
  float s2 = v.x*v.x + v.y*v.y + v.z*v.z + v.w*v.w;
  #pragma unroll
  for (int off=1; off<64; off<<=1) { s += __shfl_xor(s, off); s2 += __shfl_xor(s2, off); }
  __shared__ float ps[4], ps2[4];
  const int w = t >> 6;
  if ((t & 63) == 0) { ps[w] = s; ps2[w] = s2; }
  __syncthreads();
  s  = ps[0] + ps[1] + ps[2] + ps[3];
  s2 = ps2[0] + ps2[1] + ps2[2] + ps2[3];
  const float mu = s * (1.f/1024.f);
  const float var = s2 * (1.f/1024.f) - mu*mu;
  const float rs = rsqrtf(var + 1e-5f);
  float4 gg = ((const float4*)g)[t];
  float4 bv = ((const float4*)bb)[t];
  u16x4 o = { f2bf((v.x-mu)*rs*gg.x + bv.x),
              f2bf((v.y-mu)*rs*gg.y + bv.y),
              f2bf((v.z-mu)*rs*gg.z + bv.z),
              f2bf((v.w-mu)*rs*gg.w + bv.w) };
  ((u16x4*)out)[row*256 + t] = o;
}

// ---------------- launcher ----------------

extern "C" void kernel_launch(void* const* d_in, const int* in_sizes, int n_in,
                              void* d_out, int out_size, void* d_ws, size_t ws_size,
                              hipStream_t stream)
{
  (void)in_sizes; (void)n_in; (void)out_size; (void)ws_size;
  const float* x   = (const float*)d_in[0];
  const float* ht  = (const float*)d_in[1];
  const float* ha  = (const float*)d_in[2];
  const float* pp  = (const float*)d_in[3];
  const float* Wq  = (const float*)d_in[4];
  const float* bq  = (const float*)d_in[5];
  const float* Wk  = (const float*)d_in[6];
  const float* bk  = (const float*)d_in[7];
  const float* Wv  = (const float*)d_in[8];
  const float* bv  = (const float*)d_in[9];
  const float* Wo  = (const float*)d_in[10];
  const float* bo  = (const float*)d_in[11];
  const float* gat = (const float*)d_in[12];
  const float* lng = (const float*)d_in[13];
  const float* lnb = (const float*)d_in[14];
  const float* Wf  = (const float*)d_in[15];
  const float* bfp = (const float*)d_in[16];
  float* out = (float*)d_out;

  char* ws = (char*)d_ws;
  size_t off = 0;
  auto alloc = [&](size_t bytes) { void* r = ws + off; off += (bytes + 255) & ~255ull; return r; };
  u16* M    = (u16*)alloc(13312ull*1024*2);  // 27.26 MB (dead after QKV gemm; Vtg overlays)
  u16* Wqkv = (u16*)alloc(3072ull*1024*2);   //  6.29 MB (dead after QKV gemm)
  u16* Wobf = (u16*)alloc(1024ull*1024*2);
  u16* Wfbf = (u16*)alloc(1024ull*1024*2);
  u16* Qb   = (u16*)alloc(8192ull*1024*2);   // dead after flash
  u16* Kb2  = (u16*)alloc(13312ull*1024*2);
  u16* Vb2  = (u16*)alloc(13312ull*1024*2);
  u16* Ab   = (u16*)alloc(8192ull*1024*2);
  u16* Vtg  = M;                             // V^T [b][1024][1664], exact-size overlay on M
  float* Y  = (float*)M;                     // fp32 y overlays M+Wqkv after flash
  u16* Ln   = Qb;                            // overlay onto Qb

  hipLaunchKernelGGL(cvt_weights, dim3(5120), dim3(256), 0, stream,
                     Wq, Wk, Wv, Wo, Wf, Wqkv, Wobf, Wfbf);
  hipLaunchKernelGGL(build_m, dim3(13312), dim3(256), 0, stream, x, ht, ha, pp, M);
  hipLaunchKernelGGL((gemm_bt<0>), dim3(104, 24), dim3(256), 0, stream,
                     M, Wqkv, 1024, bq, bk, bv,
                     (const void*)gat, (void*)Qb, (void*)Kb2, (void*)Vb2);
  hipLaunchKernelGGL(vtrans, dim3(26, 16, 8), dim3(256), 0, stream, Vb2, Vtg);
  hipLaunchKernelGGL(flash_attn, dim3(512), dim3(256), 0, stream, Qb, Kb2, Vtg, Ab);
  hipLaunchKernelGGL((gemm_bt<1>), dim3(64, 8), dim3(256), 0, stream,
                     Ab, Wobf, 1024, bo, nullptr, nullptr,
                     (const void*)x, (void*)Y, nullptr, nullptr);
  hipLaunchKernelGGL(ln_kernel, dim3(8192), dim3(256), 0, stream, Y, lng, lnb, Ln);
  hipLaunchKernelGGL((gemm_bt<2>), dim3(64, 8), dim3(256), 0, stream,
                     Ln, Wfbf, 1024, bfp, nullptr, nullptr,
                     nullptr, (void*)out, nullptr, nullptr);
}

// Round 4
// 487.033 us; speedup vs baseline: 1.2145x; 1.0052x over previous
//
#include <hip/hip_runtime.h>
#include <hip/hip_bf16.h>
#include <math.h>

typedef unsigned short u16;
typedef __attribute__((ext_vector_type(8))) short s16x8;
typedef __attribute__((ext_vector_type(4))) float f32x4;
typedef __attribute__((ext_vector_type(16))) float f32x16;
typedef __attribute__((ext_vector_type(4))) unsigned short u16x4;

__device__ __forceinline__ u16 f2bf(float f) {
  union { float f; unsigned u; } v; v.f = f;
  unsigned r = (v.u + 0x7FFFu + ((v.u >> 16) & 1u)) >> 16;
  return (u16)r;
}

__device__ __forceinline__ void gload16(const void* g, void* l) {
  __builtin_amdgcn_global_load_lds((const __attribute__((address_space(1))) unsigned int*)g,
                                   (__attribute__((address_space(3))) unsigned int*)l, 16, 0, 0);
}

__device__ __forceinline__ unsigned cvt_pk_bf16(float a, float b) {
  unsigned r;
  asm("v_cvt_pk_bf16_f32 %0, %1, %2" : "=v"(r) : "v"(a), "v"(b));
  return r;
}

// ---------------- elementwise prep ----------------

__global__ __launch_bounds__(256) void cvt_weights(
    const float* __restrict__ wq, const float* __restrict__ wk, const float* __restrict__ wv,
    const float* __restrict__ wo, const float* __restrict__ wf,
    u16* __restrict__ wqkv, u16* __restrict__ wobf, u16* __restrict__ wfbf)
{
  int i = blockIdx.x * 256 + threadIdx.x;   // 5 * 262144 float4 units
  int which = i >> 18;
  int idx = i & 262143;
  const float* src = which==0 ? wq : which==1 ? wk : which==2 ? wv : which==3 ? wo : wf;
  float4 v = ((const float4*)src)[idx];
  u16x4 o = { f2bf(v.x), f2bf(v.y), f2bf(v.z), f2bf(v.w) };
  u16* dst = which < 3 ? (wqkv + (size_t)which*1048576) : (which==3 ? wobf : wfbf);
  ((u16x4*)dst)[idx] = o;
}

// M[b*1664 + s] = rows of [x(1024); h_a(64); p(64); h_t(512)] per batch, bf16
__global__ __launch_bounds__(256) void build_m(
    const float* __restrict__ x, const float* __restrict__ ht,
    const float* __restrict__ ha, const float* __restrict__ p,
    u16* __restrict__ M)
{
  int row = blockIdx.x; int t = threadIdx.x;
  int b = row / 1664, s = row % 1664;
  const float* src;
  if (s < 1024)      src = x  + (size_t)(b*1024 + s)*1024;
  else if (s < 1088) src = ha + (size_t)(b*64 + (s-1024))*1024;
  else if (s < 1152) src = p  + (size_t)(b*64 + (s-1088))*1024;
  else               src = ht + (size_t)(b*512 + (s-1152))*1024;
  float4 v = ((const float4*)src)[t];
  u16x4 o = { f2bf(v.x), f2bf(v.y), f2bf(v.z), f2bf(v.w) };
  ((u16x4*)(M + (size_t)row*1024))[t] = o;
}

// ---------------- 256x256 8-phase QKV GEMM (T2+T3+T4+T5), K=1024 ----------------
// C[13312,3072] = M[13312,1024] @ Wqkv[3072,1024]^T, fused QKV epilogue.

#define PHASE(D, QM, QN, STAGE_STMT, ENDSYNC)                                    \
  {                                                                              \
    s16x8 af_[4][2], bf_[2][2];                                                  \
    _Pragma("unroll")                                                            \
    for (int mi2=0; mi2<4; ++mi2) {                                              \
      const int r = wm*128 + (QM*4+mi2)*16 + l15;                                \
      _Pragma("unroll")                                                          \
      for (int ks=0; ks<2; ++ks)                                                 \
        af_[mi2][ks] = *(const s16x8*)(As[D] + r*64 + (((ks*4+lg) ^ (r&7))<<3)); \
    }                                                                            \
    _Pragma("unroll")                                                            \
    for (int ni2=0; ni2<2; ++ni2) {                                              \
      const int r = wn*64 + (QN*2+ni2)*16 + l15;                                 \
      _Pragma("unroll")                                                          \
      for (int ks=0; ks<2; ++ks)                                                 \
        bf_[ni2][ks] = *(const s16x8*)(Bs[D] + r*64 + (((ks*4+lg) ^ (r&7))<<3)); \
    }                                                                            \
    STAGE_STMT;                                                                  \
    __builtin_amdgcn_s_barrier();                                                \
    asm volatile("s_waitcnt lgkmcnt(0)" ::: "memory");                           \
    __builtin_amdgcn_s_setprio(1);                                               \
    _Pragma("unroll")                                                            \
    for (int mi2=0; mi2<4; ++mi2)                                                \
      _Pragma("unroll")                                                          \
      for (int ni2=0; ni2<2; ++ni2)                                              \
        _Pragma("unroll")                                                        \
        for (int ks=0; ks<2; ++ks)                                               \
          acc[QM*4+mi2][QN*2+ni2] = __builtin_amdgcn_mfma_f32_16x16x32_bf16(     \
              af_[mi2][ks], bf_[ni2][ks], acc[QM*4+mi2][QN*2+ni2], 0,0,0);       \
    __builtin_amdgcn_s_setprio(0);                                               \
    ENDSYNC;                                                                     \
  }

__global__ __launch_bounds__(512, 2) void gemm256_qkv(
    const u16* __restrict__ A, const u16* __restrict__ Bw,
    const float* __restrict__ bias_q, const float* __restrict__ bias_k,
    const float* __restrict__ bias_v, const float* __restrict__ gat,
    u16* __restrict__ Qb, u16* __restrict__ Kb, u16* __restrict__ Vb)
{
  __shared__ __align__(16) u16 As[2][256*64];
  __shared__ __align__(16) u16 Bs[2][256*64];

  const int tid = threadIdx.x;
  const int l = tid & 63;
  const int w = tid >> 6;            // 0..7
  const int wm = w >> 2, wn = w & 3; // 2x4 wave grid
  const int l15 = l & 15, lg = l >> 4;
  const int w8 = w * 8;

  // bijective XCD swizzle: 624 blocks = 8 * 78; nt-major within XCD chunk
  const int b0 = blockIdx.x;
  const int swz = (b0 & 7) * 78 + (b0 >> 3);
  const int mt = swz % 52, nt = swz / 52;
  const int m0 = mt * 256, n0 = nt * 256;

  if (n0 < 1024) {   // Q-region column tiles: skip all-non-token row tiles
    const int s0 = m0 % 1664;
    if (s0 >= 1024 && s0 <= 1408) return;
  }

  // stage half-tiles: A-half h = rows {(r>>6)&1 == h}; B-half h = rows {(r>>5)&1 == h}
  auto stA = [&](int d, int h, int kt) {
    #pragma unroll
    for (int i=0;i<2;++i) {
      const int r0 = i*128 + h*64 + w8;
      const int r  = r0 + (l >> 3);
      const int sck = (l & 7) ^ (r & 7);
      gload16(A + (size_t)(m0 + r)*1024 + kt*64 + sck*8, (void*)(As[d] + r0*64));
    }
  };
  auto stB = [&](int d, int h, int kt) {
    #pragma unroll
    for (int i=0;i<2;++i) {
      const int blk = i*2 + (w>>2);
      const int r0 = (w&3)*8 + blk*64 + h*32;
      const int r  = r0 + (l >> 3);
      const int sck = (l & 7) ^ (r & 7);
      gload16(Bw + (size_t)(n0 + r)*1024 + kt*64 + sck*8, (void*)(Bs[d] + r0*64));
    }
  };

  f32x4 acc[8][4];
  #pragma unroll
  for (int i=0;i<8;++i)
    #pragma unroll
    for (int j=0;j<4;++j) acc[i][j] = (f32x4){0,0,0,0};

  // prologue: tile0 all halves + tile1 {B0, A1}; then wait tile0 resident
  stB(0,0,0); stA(0,1,0); stA(0,0,0); stB(0,1,0); stB(1,0,1); stA(1,1,1);
  asm volatile("s_waitcnt vmcnt(4)\ns_barrier" ::: "memory");

  for (int t = 0; t < 16; ++t) {
    const int d = t & 1;
    const int e = d ^ 1;
    // q0: quad(0,0), stage (t+1).A0 -> e
    PHASE(d, 0, 0, if (t+1 < 16) stA(e, 0, t+1), __builtin_amdgcn_s_barrier())
    // q1: quad(1,0), stage (t+1).B1 -> e ; vmcnt(8): tile t fully resident incl B1
    PHASE(d, 1, 0, if (t+1 < 16) stB(e, 1, t+1),
          asm volatile("s_waitcnt vmcnt(8)\ns_barrier" ::: "memory"))
    // q2: quad(1,1), stage (t+2).B0 -> d (B0 slot freed after q1)
    PHASE(d, 1, 1, if (t+2 < 16) stB(d, 0, t+2), __builtin_amdgcn_s_barrier())
    // q3: quad(0,1), stage (t+2).A1 -> d (A1 slot freed after q2)
    PHASE(d, 0, 1, if (t+2 < 16) stA(d, 1, t+2), )
    if (t <= 13)      asm volatile("s_waitcnt vmcnt(6)\ns_barrier" ::: "memory");
    else if (t == 14) asm volatile("s_waitcnt vmcnt(0)\ns_barrier" ::: "memory");
    else              __builtin_amdgcn_s_barrier();
  }

  // epilogue: fused QKV write
  const float ratio = tanhf(gat[0]);
  #pragma unroll
  for (int mi=0;mi<8;++mi) {
    #pragma unroll
    for (int ni=0;ni<4;++ni) {
      #pragma unroll
      for (int rr=0;rr<4;++rr) {
        const int row = m0 + wm*128 + mi*16 + lg*4 + rr;
        const int col = n0 + wn*64 + ni*16 + l15;
        const int b = row / 1664, s = row % 1664;
        const float a = acc[mi][ni][rr];
        if (col < 1024) {
          if (s < 1024) {
            float v = a + bias_q[col];
            Qb[(size_t)(b*1024 + s)*1024 + col] = f2bf(v * 0.08838834764831845f);
          }
        } else if (col < 2048) {
          float v = a + bias_k[col-1024];
          if (s >= 1152) v *= ratio;
          Kb[(size_t)row*1024 + (col-1024)] = f2bf(v);
        } else {
          float v = a + bias_v[col-2048];
          Vb[(size_t)row*1024 + (col-2048)] = f2bf(v);
        }
      }
    }
  }
}

// ---------------- GEMM: C[M,N] = A[M,K] @ B[N,K]^T, m97-style 128x128 tile ----------------
// EPI 1: +bo +x -> fp32 y. EPI 2: +bf, relu -> fp32 out.

template<int EPI>
__global__ __launch_bounds__(256) void gemm_bt(
    const u16* __restrict__ A, const u16* __restrict__ Bw, int K,
    const float* __restrict__ bias0,
    const void* p0, void* p1)
{
  __shared__ __align__(16) u16 As[128*32];
  __shared__ __align__(16) u16 Bs[128*32];
  const int tid = threadIdx.x;
  const int l = tid & 63;
  const int w = tid >> 6;
  const int m0 = blockIdx.x * 128;
  const int n0 = blockIdx.y * 128;

  const int wr = w >> 1, wc = w & 1;
  const int l15 = l & 15, lg = l >> 4;

  f32x4 acc[4][4];
  #pragma unroll
  for (int i=0;i<4;++i)
    #pragma unroll
    for (int j=0;j<4;++j) acc[i][j] = (f32x4){0,0,0,0};

  const int kiters = K >> 5;
  for (int kt = 0; kt < kiters; ++kt) {
    __syncthreads();
    #pragma unroll
    for (int c = 0; c < 2; ++c) {
      const int rbase = w*32 + c*16;
      const int rl = rbase + (l >> 2);
      const int kb = kt*32 + (l & 3)*8;
      gload16(A  + (size_t)(m0 + rl)*K + kb, (void*)(As + rbase*32));
      gload16(Bw + (size_t)(n0 + rl)*K + kb, (void*)(Bs + rbase*32));
    }
    __syncthreads();
    s16x8 av[4];
    #pragma unroll
    for (int mi=0;mi<4;++mi)
      av[mi] = *(const s16x8*)(As + (wr*64 + mi*16 + l15)*32 + lg*8);
    #pragma unroll
    for (int ni=0;ni<4;++ni) {
      s16x8 bv = *(const s16x8*)(Bs + (wc*64 + ni*16 + l15)*32 + lg*8);
      #pragma unroll
      for (int mi=0;mi<4;++mi)
        acc[mi][ni] = __builtin_amdgcn_mfma_f32_16x16x32_bf16(av[mi], bv, acc[mi][ni], 0,0,0);
    }
  }

  #pragma unroll
  for (int mi=0;mi<4;++mi) {
    #pragma unroll
    for (int ni=0;ni<4;++ni) {
      #pragma unroll
      for (int r=0;r<4;++r) {
        const int row = m0 + wr*64 + mi*16 + lg*4 + r;
        const int col = n0 + wc*64 + ni*16 + l15;
        if constexpr (EPI == 1) {
          float v = acc[mi][ni][r] + bias0[col] + ((const float*)p0)[(size_t)row*1024 + col];
          ((float*)p1)[(size_t)row*1024 + col] = v;
        } else {
          float v = acc[mi][ni][r] + bias0[col];
          ((float*)p1)[(size_t)row*1024 + col] = fmaxf(v, 0.f);
        }
      }
    }
  }
}

// ---------------- V transpose: Vt[b][c=1024][s=1664] = V[b][s][c] ----------------

__global__ __launch_bounds__(256) void vtrans(
    const u16* __restrict__ V, u16* __restrict__ Vt)
{
  __shared__ u16 Ls[64][68];
  const int st = blockIdx.x, dt = blockIdx.y, b = blockIdx.z;
  const int t = threadIdx.x;
  const int rq = t >> 4, c4 = t & 15;
  #pragma unroll
  for (int i=0;i<4;++i) {
    const int r = i*16 + rq;
    u16x4 v = *(const u16x4*)(V + ((size_t)(b*1664 + st*64 + r))*1024 + dt*64 + c4*4);
    Ls[r][c4*4+0] = v[0]; Ls[r][c4*4+1] = v[1]; Ls[r][c4*4+2] = v[2]; Ls[r][c4*4+3] = v[3];
  }
  __syncthreads();
  #pragma unroll
  for (int i=0;i<4;++i) {
    const int dr = i*16 + rq;
    u16x4 ov = { Ls[c4*4+0][dr], Ls[c4*4+1][dr], Ls[c4*4+2][dr], Ls[c4*4+3][dr] };
    *(u16x4*)(Vt + ((size_t)(b*1024 + dt*64 + dr))*1664 + st*64 + c4*4) = ov;
  }
}

// ---------------- flash attention, 32x32 swapped-QK, S=1664, D=128 ----------------

__global__ __launch_bounds__(256, 2) void flash_attn(
    const u16* __restrict__ Q, const u16* __restrict__ Kb, const u16* __restrict__ Vtg,
    u16* __restrict__ O)
{
  __shared__ __align__(16) u16 Kl[2][64*128];   // [s][16 chunks], chunk low3 ^= s&7
  __shared__ __align__(16) u16 Vl[2][128*64];   // [d][8 chunks], chunk ^= d&7

  const int tid = threadIdx.x;
  const int l = tid & 63;
  const int w = tid >> 6;
  const int l31 = l & 31;
  const int hi = l >> 5;
  const int bh = blockIdx.x & 63;
  const int qt = blockIdx.x >> 6;
  const int b = bh >> 3, h = bh & 7;
  const int colh = h * 128;
  const int q0 = qt*128 + w*32;

  s16x8 qf[8];
  {
    const size_t qrow = (size_t)(b*1024 + q0 + l31)*1024 + colh;
    #pragma unroll
    for (int kc=0;kc<8;++kc)
      qf[kc] = *(const s16x8*)(Q + qrow + kc*16 + hi*8);
  }

  f32x16 oacc[4];
  #pragma unroll
  for (int dt2=0;dt2<4;++dt2)
    #pragma unroll
    for (int i=0;i<16;++i) oacc[dt2][i] = 0.f;
  float m_run = -INFINITY, l_run = 0.f;

  const size_t kbase  = (size_t)(b*1664)*1024 + colh;
  const size_t vtbase = (size_t)(b*1024 + colh)*1664;

  auto stage = [&](int st, int nb) {
    const int s0 = st*64;
    #pragma unroll
    for (int i=0;i<4;++i) {
      const int e = i*256 + tid;
      const int sl = e >> 4, c = e & 15;
      const int g = (c & 8) | ((c ^ sl) & 7);
      gload16(Kb + kbase + (size_t)(s0 + sl)*1024 + g*8,
              (void*)(Kl[nb] + (i*256 + w*64)*8));
    }
    #pragma unroll
    for (int i=0;i<4;++i) {
      const int e = i*256 + tid;
      const int d = e >> 3, c3 = e & 7;
      const int g3 = (c3 ^ d) & 7;
      gload16(Vtg + vtbase + (size_t)d*1664 + s0 + g3*8,
              (void*)(Vl[nb] + (i*256 + w*64)*8));
    }
  };

  stage(0, 0);
  __syncthreads();
  int cur = 0;

  for (int st=0; st<26; ++st) {
    if (st + 1 < 26) stage(st + 1, cur ^ 1);

    f32x16 sacc[2];
    #pragma unroll
    for (int stile=0; stile<2; ++stile) {
      #pragma unroll
      for (int i=0;i<16;++i) sacc[stile][i] = 0.f;
      #pragma unroll
      for (int kc=0; kc<8; ++kc) {
        const int sl = stile*32 + l31;
        const int gc = kc*2 + hi;
        const int cl = (gc & 8) | ((gc ^ sl) & 7);
        s16x8 kf = *(const s16x8*)(Kl[cur] + sl*128 + cl*8);
        sacc[stile] = __builtin_amdgcn_mfma_f32_32x32x16_bf16(kf, qf[kc], sacc[stile], 0,0,0);
      }
    }

    float tm[8];
    #pragma unroll
    for (int i=0;i<8;++i)
      tm[i] = fmaxf(fmaxf(sacc[0][i], sacc[0][i+8]), fmaxf(sacc[1][i], sacc[1][i+8]));
    float pm = fmaxf(fmaxf(fmaxf(tm[0],tm[1]), fmaxf(tm[2],tm[3])),
                     fmaxf(fmaxf(tm[4],tm[5]), fmaxf(tm[6],tm[7])));
    pm = fmaxf(pm, __shfl_xor(pm, 32));

    if (__any(pm > m_run + 8.f)) {
      const float mnew = fmaxf(m_run, pm);
      const float alpha = __expf(m_run - mnew);
      m_run = mnew;
      l_run *= alpha;
      #pragma unroll
      for (int r=0;r<16;++r) {
        const int qr = (r&3) + 8*(r>>2) + 4*hi;
        const float ar = __shfl(alpha, qr);
        #pragma unroll
        for (int dt2=0;dt2<4;++dt2) oacc[dt2][r] *= ar;
      }
    }

    float ps = 0.f;
    #pragma unroll
    for (int stile=0; stile<2; ++stile)
      #pragma unroll
      for (int i=0;i<16;++i) {
        const float v = __expf(sacc[stile][i] - m_run);
        sacc[stile][i] = v;
        ps += v;
      }
    ps += __shfl_xor(ps, 32);
    l_run += ps;

    s16x8 pf[4];
    #pragma unroll
    for (int kc2=0; kc2<4; ++kc2) {
      const int stile = kc2 >> 1;
      const int rb = (kc2 & 1) * 8;
      const unsigned A = cvt_pk_bf16(sacc[stile][rb+0], sacc[stile][rb+1]);
      const unsigned B = cvt_pk_bf16(sacc[stile][rb+2], sacc[stile][rb+3]);
      const unsigned C = cvt_pk_bf16(sacc[stile][rb+4], sacc[stile][rb+5]);
      const unsigned D = cvt_pk_bf16(sacc[stile][rb+6], sacc[stile][rb+7]);
      const unsigned x1 = (unsigned)__shfl_xor((int)(hi ? A : C), 32);
      const unsigned x2 = (unsigned)__shfl_xor((int)(hi ? B : D), 32);
      union { unsigned u[4]; s16x8 v; } fr;
      fr.u[0] = hi ? x1 : A;
      fr.u[1] = hi ? x2 : B;
      fr.u[2] = hi ? C : x1;
      fr.u[3] = hi ? D : x2;
      pf[kc2] = fr.v;
    }

    #pragma unroll
    for (int dt2=0; dt2<4; ++dt2) {
      const int d = dt2*32 + l31;
      #pragma unroll
      for (int kc2=0; kc2<4; ++kc2) {
        const int g3 = kc2*2 + hi;
        const int cl3 = (g3 ^ d) & 7;
        s16x8 vf = *(const s16x8*)(Vl[cur] + d*64 + cl3*8);
        oacc[dt2] = __builtin_amdgcn_mfma_f32_32x32x16_bf16(pf[kc2], vf, oacc[dt2], 0,0,0);
      }
    }

    __syncthreads();
    cur ^= 1;
  }

  const float linv = 1.f / l_run;
  #pragma unroll
  for (int r=0;r<16;++r) {
    const int qr = (r&3) + 8*(r>>2) + 4*hi;
    const float lr = __shfl(linv, qr);
    const size_t row = (size_t)(b*1024 + q0 + qr)*1024 + colh;
    #pragma unroll
    for (int dt2=0;dt2<4;++dt2)
      O[row + dt2*32 + l31] = f2bf(oacc[dt2][r] * lr);
  }
}

// ---------------- LayerNorm (block per row of 1024) ----------------

__global__ __launch_bounds__(256) void ln_kernel(
    const float* __restrict__ y, const float* __restrict__ g, const float* __restrict__ bb,
    u16* __restrict__ out)
{
  const int row = blockIdx.x, t = threadIdx.x;
  float4 v = ((const float4*)y)[row*256 + t];
  float s  = v.x + v.y + v.z + v.w;
  float s2 = v.x*v.x + v.y*v.y + v.z*v.z + v.w*v.w;
  #pragma unroll
  for (int off=1; off<64; off<<=1) { s += __shfl_xor(s, off); s2 += __shfl_xor(s2, off); }
  __shared__ float ps[4], ps2[4];
  const int w = t >> 6;
  if ((t & 63) == 0) { ps[w] = s; ps2[w] = s2; }
  __syncthreads();
  s  = ps[0] + ps[1] + ps[2] + ps[3];
  s2 = ps2[0] + ps2[1] + ps2[2] + ps2[3];
  const float mu = s * (1.f/1024.f);
  const float var = s2 * (1.f/1024.f) - mu*mu;
  const float rs = rsqrtf(var + 1e-5f);
  float4 gg = ((const float4*)g)[t];
  float4 bv = ((const float4*)bb)[t];
  u16x4 o = { f2bf((v.x-mu)*rs*gg.x + bv.x),
              f2bf((v.y-mu)*rs*gg.y + bv.y),
              f2bf((v.z-mu)*rs*gg.z + bv.z),
              f2bf((v.w-mu)*rs*gg.w + bv.w) };
  ((u16x4*)out)[row*256 + t] = o;
}

// ---------------- launcher ----------------

extern "C" void kernel_launch(void* const* d_in, const int* in_sizes, int n_in,
                              void* d_out, int out_size, void* d_ws, size_t ws_size,
                              hipStream_t stream)
{
  (void)in_sizes; (void)n_in; (void)out_size; (void)ws_size;
  const float* x   = (const float*)d_in[0];
  const float* ht  = (const float*)d_in[1];
  const float* ha  = (const float*)d_in[2];
  const float* pp  = (const float*)d_in[3];
  const float* Wq  = (const float*)d_in[4];
  const float* bq  = (const float*)d_in[5];
  const float* Wk  = (const float*)d_in[6];
  const float* bk  = (const float*)d_in[7];
  const float* Wv  = (const float*)d_in[8];
  const float* bv  = (const float*)d_in[9];
  const float* Wo  = (const float*)d_in[10];
  const float* bo  = (const float*)d_in[11];
  const float* gat = (const float*)d_in[12];
  const float* lng = (const float*)d_in[13];
  const float* lnb = (const float*)d_in[14];
  const float* Wf  = (const float*)d_in[15];
  const float* bfp = (const float*)d_in[16];
  float* out = (float*)d_out;

  char* ws = (char*)d_ws;
  size_t off = 0;
  auto alloc = [&](size_t bytes) { void* r = ws + off; off += (bytes + 255) & ~255ull; return r; };
  u16* M    = (u16*)alloc(13312ull*1024*2);  // dead after QKV gemm; Vtg/Y overlay
  u16* Wqkv = (u16*)alloc(3072ull*1024*2);   // dead after QKV gemm
  u16* Wobf = (u16*)alloc(1024ull*1024*2);
  u16* Wfbf = (u16*)alloc(1024ull*1024*2);
  u16* Qb   = (u16*)alloc(8192ull*1024*2);   // dead after flash
  u16* Kb2  = (u16*)alloc(13312ull*1024*2);
  u16* Vb2  = (u16*)alloc(13312ull*1024*2);
  u16* Ab   = (u16*)alloc(8192ull*1024*2);
  u16* Vtg  = M;                             // V^T overlay on M
  float* Y  = (float*)M;                     // fp32 y overlays M+Wqkv after flash
  u16* Ln   = Qb;

  hipLaunchKernelGGL(cvt_weights, dim3(5120), dim3(256), 0, stream,
                     Wq, Wk, Wv, Wo, Wf, Wqkv, Wobf, Wfbf);
  hipLaunchKernelGGL(build_m, dim3(13312), dim3(256), 0, stream, x, ht, ha, pp, M);
  hipLaunchKernelGGL(gemm256_qkv, dim3(624), dim3(512), 0, stream,
                     M, Wqkv, bq, bk, bv, gat, Qb, Kb2, Vb2);
  hipLaunchKernelGGL(vtrans, dim3(26, 16, 8), dim3(256), 0, stream, Vb2, Vtg);
  hipLaunchKernelGGL(flash_attn, dim3(512), dim3(256), 0, stream, Qb, Kb2, Vtg, Ab);
  hipLaunchKernelGGL((gemm_bt<1>), dim3(64, 8), dim3(256), 0, stream,
                     Ab, Wobf, 1024, bo, (const void*)x, (void*)Y);
  hipLaunchKernelGGL(ln_kernel, dim3(8192), dim3(256), 0, stream, Y, lng, lnb, Ln);
  hipLaunchKernelGGL((gemm_bt<2>), dim3(64, 8), dim3(256), 0, stream,
                     Ln, Wfbf, 1024, bfp, nullptr, (void*)out);
}

// Round 6
// 475.610 us; speedup vs baseline: 1.2437x; 1.0240x over previous
//
#include <hip/hip_runtime.h>
#include <hip/hip_bf16.h>
#include <math.h>

typedef unsigned short u16;
typedef __attribute__((ext_vector_type(8))) short s16x8;
typedef __attribute__((ext_vector_type(4))) float f32x4;
typedef __attribute__((ext_vector_type(16))) float f32x16;
typedef __attribute__((ext_vector_type(4))) unsigned short u16x4;

__device__ __forceinline__ u16 f2bf(float f) {
  union { float f; unsigned u; } v; v.f = f;
  unsigned r = (v.u + 0x7FFFu + ((v.u >> 16) & 1u)) >> 16;
  return (u16)r;
}

__device__ __forceinline__ void gload16(const void* g, void* l) {
  __builtin_amdgcn_global_load_lds((const __attribute__((address_space(1))) unsigned int*)g,
                                   (__attribute__((address_space(3))) unsigned int*)l, 16, 0, 0);
}

__device__ __forceinline__ unsigned cvt_pk_bf16(float a, float b) {
  unsigned r;
  asm("v_cvt_pk_bf16_f32 %0, %1, %2" : "=v"(r) : "v"(a), "v"(b));
  return r;
}

// ---------------- elementwise prep ----------------

__global__ __launch_bounds__(256) void cvt_weights(
    const float* __restrict__ wq, const float* __restrict__ wk, const float* __restrict__ wv,
    const float* __restrict__ wo, const float* __restrict__ wf,
    u16* __restrict__ wqkv, u16* __restrict__ wobf, u16* __restrict__ wfbf)
{
  int i = blockIdx.x * 256 + threadIdx.x;   // 5 * 262144 float4 units
  int which = i >> 18;
  int idx = i & 262143;
  const float* src = which==0 ? wq : which==1 ? wk : which==2 ? wv : which==3 ? wo : wf;
  float4 v = ((const float4*)src)[idx];
  u16x4 o = { f2bf(v.x), f2bf(v.y), f2bf(v.z), f2bf(v.w) };
  u16* dst = which < 3 ? (wqkv + (size_t)which*1048576) : (which==3 ? wobf : wfbf);
  ((u16x4*)dst)[idx] = o;
}

// M[b*1664 + s] = rows of [x(1024); h_a(64); p(64); h_t(512)] per batch, bf16
__global__ __launch_bounds__(256) void build_m(
    const float* __restrict__ x, const float* __restrict__ ht,
    const float* __restrict__ ha, const float* __restrict__ p,
    u16* __restrict__ M)
{
  int row = blockIdx.x; int t = threadIdx.x;
  int b = row / 1664, s = row % 1664;
  const float* src;
  if (s < 1024)      src = x  + (size_t)(b*1024 + s)*1024;
  else if (s < 1088) src = ha + (size_t)(b*64 + (s-1024))*1024;
  else if (s < 1152) src = p  + (size_t)(b*64 + (s-1088))*1024;
  else               src = ht + (size_t)(b*512 + (s-1152))*1024;
  float4 v = ((const float4*)src)[t];
  u16x4 o = { f2bf(v.x), f2bf(v.y), f2bf(v.z), f2bf(v.w) };
  ((u16x4*)(M + (size_t)row*1024))[t] = o;
}

// ---------------- 256x256 8-phase QKV GEMM (T2+T3+T4+T5), K=1024 ----------------
// Read-once quadrant schedule: q0=(0,0) reads A0+B0, q1=(0,1) reads B1,
// q2=(1,1) reads A1, q3=(1,0) reads nothing (holds A1,B0 in regs).
// 24 ds_read_b128/wave/K-tile (the geometric minimum for this wave-tiling).

#define RD_A(dst, D, QM)                                                         \
  _Pragma("unroll")                                                              \
  for (int mi2=0; mi2<4; ++mi2) {                                                \
    const int r = wm*128 + ((QM)*4+mi2)*16 + l15;                                \
    _Pragma("unroll")                                                            \
    for (int ks=0; ks<2; ++ks)                                                   \
      dst[mi2][ks] = *(const s16x8*)(As[D] + r*64 + (((ks*4+lg) ^ (r&7))<<3));   \
  }

#define RD_B(dst, D, QN)                                                         \
  _Pragma("unroll")                                                              \
  for (int ni2=0; ni2<2; ++ni2) {                                                \
    const int r = wn*64 + ((QN)*2+ni2)*16 + l15;                                 \
    _Pragma("unroll")                                                            \
    for (int ks=0; ks<2; ++ks)                                                   \
      dst[ni2][ks] = *(const s16x8*)(Bs[D] + r*64 + (((ks*4+lg) ^ (r&7))<<3));   \
  }

#define MM_Q(aq, bq, QM, QN)                                                     \
  __builtin_amdgcn_s_setprio(1);                                                 \
  _Pragma("unroll")                                                              \
  for (int mi2=0; mi2<4; ++mi2)                                                  \
    _Pragma("unroll")                                                            \
    for (int ni2=0; ni2<2; ++ni2)                                                \
      _Pragma("unroll")                                                          \
      for (int ks=0; ks<2; ++ks)                                                 \
        acc[(QM)*4+mi2][(QN)*2+ni2] = __builtin_amdgcn_mfma_f32_16x16x32_bf16(   \
            aq[mi2][ks], bq[ni2][ks], acc[(QM)*4+mi2][(QN)*2+ni2], 0,0,0);       \
  __builtin_amdgcn_s_setprio(0);

__global__ __launch_bounds__(512, 2) void gemm256_qkv(
    const u16* __restrict__ A, const u16* __restrict__ Bw,
    const float* __restrict__ bias_q, const float* __restrict__ bias_k,
    const float* __restrict__ bias_v, const float* __restrict__ gat,
    u16* __restrict__ Qb, u16* __restrict__ Kb, u16* __restrict__ Vb)
{
  __shared__ __align__(16) u16 As[2][256*64];
  __shared__ __align__(16) u16 Bs[2][256*64];

  const int tid = threadIdx.x;
  const int l = tid & 63;
  const int w = tid >> 6;            // 0..7
  const int wm = w >> 2, wn = w & 3; // 2x4 wave grid
  const int l15 = l & 15, lg = l >> 4;
  const int w8 = w * 8;

  // bijective XCD swizzle: 624 blocks = 8 * 78; nt-major within XCD chunk
  const int b0 = blockIdx.x;
  const int swz = (b0 & 7) * 78 + (b0 >> 3);
  const int mt = swz % 52, nt = swz / 52;
  const int m0 = mt * 256, n0 = nt * 256;

  if (n0 < 1024) {   // Q-region column tiles: skip all-non-token row tiles
    const int s0 = m0 % 1664;
    if (s0 >= 1024 && s0 <= 1408) return;
  }

  // stage half-tiles: A-half h = rows {(r>>6)&1 == h}; B-half h = rows {(r>>5)&1 == h}
  auto stA = [&](int d, int h, int kt) {
    #pragma unroll
    for (int i=0;i<2;++i) {
      const int r0 = i*128 + h*64 + w8;
      const int r  = r0 + (l >> 3);
      const int sck = (l & 7) ^ (r & 7);
      gload16(A + (size_t)(m0 + r)*1024 + kt*64 + sck*8, (void*)(As[d] + r0*64));
    }
  };
  auto stB = [&](int d, int h, int kt) {
    #pragma unroll
    for (int i=0;i<2;++i) {
      const int blk = i*2 + (w>>2);
      const int r0 = (w&3)*8 + blk*64 + h*32;
      const int r  = r0 + (l >> 3);
      const int sck = (l & 7) ^ (r & 7);
      gload16(Bw + (size_t)(n0 + r)*1024 + kt*64 + sck*8, (void*)(Bs[d] + r0*64));
    }
  };

  f32x4 acc[8][4];
  #pragma unroll
  for (int i=0;i<8;++i)
    #pragma unroll
    for (int j=0;j<4;++j) acc[i][j] = (f32x4){0,0,0,0};

  // prologue: tile0 all halves + tile1 {B0, A1}; then wait tile0 resident
  stB(0,0,0); stA(0,1,0); stA(0,0,0); stB(0,1,0); stB(1,0,1); stA(1,1,1);
  asm volatile("s_waitcnt vmcnt(4)\ns_barrier" ::: "memory");

  for (int t = 0; t < 16; ++t) {
    const int d = t & 1;
    const int e = d ^ 1;
    s16x8 a0[4][2], a1[4][2], b0[2][2], b1[2][2];

    // q0: quad(0,0) — read A0+B0; stage (t+1).A0 -> e
    RD_A(a0, d, 0); RD_B(b0, d, 0);
    if (t+1 < 16) stA(e, 0, t+1);
    __builtin_amdgcn_s_barrier();
    asm volatile("s_waitcnt lgkmcnt(0)" ::: "memory");
    MM_Q(a0, b0, 0, 0);
    // t.B1 guaranteed resident before q1 reads it (oldest-2 of 8 outstanding)
    asm volatile("s_waitcnt vmcnt(6)\ns_barrier" ::: "memory");

    // q1: quad(0,1) — read B1 (reuse a0); stage (t+1).B1 -> e
    RD_B(b1, d, 1);
    if (t+1 < 16) stB(e, 1, t+1);
    __builtin_amdgcn_s_barrier();
    asm volatile("s_waitcnt lgkmcnt(0)" ::: "memory");
    MM_Q(a0, b1, 0, 1);
    __builtin_amdgcn_s_barrier();

    // q2: quad(1,1) — read A1 (reuse b1); stage (t+2).B0 -> d (B0 slot free after q0)
    RD_A(a1, d, 1);
    if (t+2 < 16) stB(d, 0, t+2);
    __builtin_amdgcn_s_barrier();
    asm volatile("s_waitcnt lgkmcnt(0)" ::: "memory");
    MM_Q(a1, b1, 1, 1);
    __builtin_amdgcn_s_barrier();

    // q3: quad(1,0) — no LDS reads (reuse a1, held b0); stage (t+2).A1 -> d
    if (t+2 < 16) stA(d, 1, t+2);
    MM_Q(a1, b0, 1, 0);
    if (t <= 13)      asm volatile("s_waitcnt vmcnt(6)\ns_barrier" ::: "memory");
    else if (t == 14) asm volatile("s_waitcnt vmcnt(0)\ns_barrier" ::: "memory");
    else              __builtin_amdgcn_s_barrier();
  }

  // epilogue: fused QKV write
  const float ratio = tanhf(gat[0]);
  #pragma unroll
  for (int mi=0;mi<8;++mi) {
    #pragma unroll
    for (int ni=0;ni<4;++ni) {
      #pragma unroll
      for (int rr=0;rr<4;++rr) {
        const int row = m0 + wm*128 + mi*16 + lg*4 + rr;
        const int col = n0 + wn*64 + ni*16 + l15;
        const int b = row / 1664, s = row % 1664;
        const float a = acc[mi][ni][rr];
        if (col < 1024) {
          if (s < 1024) {
            float v = a + bias_q[col];
            Qb[(size_t)(b*1024 + s)*1024 + col] = f2bf(v * 0.08838834764831845f);
          }
        } else if (col < 2048) {
          float v = a + bias_k[col-1024];
          if (s >= 1152) v *= ratio;
          Kb[(size_t)row*1024 + (col-1024)] = f2bf(v);
        } else {
          float v = a + bias_v[col-2048];
          Vb[(size_t)row*1024 + (col-2048)] = f2bf(v);
        }
      }
    }
  }
}

// ---------------- GEMM: C[M,N] = A[M,K] @ B[N,K]^T, m97-style 128x128 tile ----------------
// EPI 1: +bo +x -> fp32 y. EPI 2: +bf, relu -> fp32 out.

template<int EPI>
__global__ __launch_bounds__(256) void gemm_bt(
    const u16* __restrict__ A, const u16* __restrict__ Bw, int K,
    const float* __restrict__ bias0,
    const void* p0, void* p1)
{
  __shared__ __align__(16) u16 As[128*32];
  __shared__ __align__(16) u16 Bs[128*32];
  const int tid = threadIdx.x;
  const int l = tid & 63;
  const int w = tid >> 6;
  const int m0 = blockIdx.x * 128;
  const int n0 = blockIdx.y * 128;

  const int wr = w >> 1, wc = w & 1;
  const int l15 = l & 15, lg = l >> 4;

  f32x4 acc[4][4];
  #pragma unroll
  for (int i=0;i<4;++i)
    #pragma unroll
    for (int j=0;j<4;++j) acc[i][j] = (f32x4){0,0,0,0};

  const int kiters = K >> 5;
  for (int kt = 0; kt < kiters; ++kt) {
    __syncthreads();
    #pragma unroll
    for (int c = 0; c < 2; ++c) {
      const int rbase = w*32 + c*16;
      const int rl = rbase + (l >> 2);
      const int kb = kt*32 + (l & 3)*8;
      gload16(A  + (size_t)(m0 + rl)*K + kb, (void*)(As + rbase*32));
      gload16(Bw + (size_t)(n0 + rl)*K + kb, (void*)(Bs + rbase*32));
    }
    __syncthreads();
    s16x8 av[4];
    #pragma unroll
    for (int mi=0;mi<4;++mi)
      av[mi] = *(const s16x8*)(As + (wr*64 + mi*16 + l15)*32 + lg*8);
    #pragma unroll
    for (int ni=0;ni<4;++ni) {
      s16x8 bv = *(const s16x8*)(Bs + (wc*64 + ni*16 + l15)*32 + lg*8);
      #pragma unroll
      for (int mi=0;mi<4;++mi)
        acc[mi][ni] = __builtin_amdgcn_mfma_f32_16x16x32_bf16(av[mi], bv, acc[mi][ni], 0,0,0);
    }
  }

  #pragma unroll
  for (int mi=0;mi<4;++mi) {
    #pragma unroll
    for (int ni=0;ni<4;++ni) {
      #pragma unroll
      for (int r=0;r<4;++r) {
        const int row = m0 + wr*64 + mi*16 + lg*4 + r;
        const int col = n0 + wc*64 + ni*16 + l15;
        if constexpr (EPI == 1) {
          float v = acc[mi][ni][r] + bias0[col] + ((const float*)p0)[(size_t)row*1024 + col];
          ((float*)p1)[(size_t)row*1024 + col] = v;
        } else {
          float v = acc[mi][ni][r] + bias0[col];
          ((float*)p1)[(size_t)row*1024 + col] = fmaxf(v, 0.f);
        }
      }
    }
  }
}

// ---------------- V transpose: Vt[b][c=1024][s=1664] = V[b][s][c] ----------------

__global__ __launch_bounds__(256) void vtrans(
    const u16* __restrict__ V, u16* __restrict__ Vt)
{
  __shared__ u16 Ls[64][68];
  const int st = blockIdx.x, dt = blockIdx.y, b = blockIdx.z;
  const int t = threadIdx.x;
  const int rq = t >> 4, c4 = t & 15;
  #pragma unroll
  for (int i=0;i<4;++i) {
    const int r = i*16 + rq;
    u16x4 v = *(const u16x4*)(V + ((size_t)(b*1664 + st*64 + r))*1024 + dt*64 + c4*4);
    Ls[r][c4*4+0] = v[0]; Ls[r][c4*4+1] = v[1]; Ls[r][c4*4+2] = v[2]; Ls[r][c4*4+3] = v[3];
  }
  __syncthreads();
  #pragma unroll
  for (int i=0;i<4;++i) {
    const int dr = i*16 + rq;
    u16x4 ov = { Ls[c4*4+0][dr], Ls[c4*4+1][dr], Ls[c4*4+2][dr], Ls[c4*4+3][dr] };
    *(u16x4*)(Vt + ((size_t)(b*1024 + dt*64 + dr))*1664 + st*64 + c4*4) = ov;
  }
}

// ---------------- flash attention, 32x32 swapped-QK, S=1664, D=128 ----------------

__global__ __launch_bounds__(256, 2) void flash_attn(
    const u16* __restrict__ Q, const u16* __restrict__ Kb, const u16* __restrict__ Vtg,
    u16* __restrict__ O)
{
  __shared__ __align__(16) u16 Kl[2][64*128];   // [s][16 chunks], chunk low3 ^= s&7
  __shared__ __align__(16) u16 Vl[2][128*64];   // [d][8 chunks], chunk ^= d&7

  const int tid = threadIdx.x;
  const int l = tid & 63;
  const int w = tid >> 6;
  const int l31 = l & 31;
  const int hi = l >> 5;
  const int bh = blockIdx.x & 63;
  const int qt = blockIdx.x >> 6;
  const int b = bh >> 3, h = bh & 7;
  const int colh = h * 128;
  const int q0 = qt*128 + w*32;

  s16x8 qf[8];
  {
    const size_t qrow = (size_t)(b*1024 + q0 + l31)*1024 + colh;
    #pragma unroll
    for (int kc=0;kc<8;++kc)
      qf[kc] = *(const s16x8*)(Q + qrow + kc*16 + hi*8);
  }

  f32x16 oacc[4];
  #pragma unroll
  for (int dt2=0;dt2<4;++dt2)
    #pragma unroll
    for (int i=0;i<16;++i) oacc[dt2][i] = 0.f;
  float m_run = -INFINITY, l_run = 0.f;

  const size_t kbase  = (size_t)(b*1664)*1024 + colh;
  const size_t vtbase = (size_t)(b*1024 + colh)*1664;

  auto stage = [&](int st, int nb) {
    const int s0 = st*64;
    #pragma unroll
    for (int i=0;i<4;++i) {
      const int e = i*256 + tid;
      const int sl = e >> 4, c = e & 15;
      const int g = (c & 8) | ((c ^ sl) & 7);
      gload16(Kb + kbase + (size_t)(s0 + sl)*1024 + g*8,
              (void*)(Kl[nb] + (i*256 + w*64)*8));
    }
    #pragma unroll
    for (int i=0;i<4;++i) {
      const int e = i*256 + tid;
      const int d = e >> 3, c3 = e & 7;
      const int g3 = (c3 ^ d) & 7;
      gload16(Vtg + vtbase + (size_t)d*1664 + s0 + g3*8,
              (void*)(Vl[nb] + (i*256 + w*64)*8));
    }
  };

  stage(0, 0);
  __syncthreads();
  int cur = 0;

  for (int st=0; st<26; ++st) {
    if (st + 1 < 26) stage(st + 1, cur ^ 1);

    f32x16 sacc[2];
    #pragma unroll
    for (int stile=0; stile<2; ++stile) {
      #pragma unroll
      for (int i=0;i<16;++i) sacc[stile][i] = 0.f;
      #pragma unroll
      for (int kc=0; kc<8; ++kc) {
        const int sl = stile*32 + l31;
        const int gc = kc*2 + hi;
        const int cl = (gc & 8) | ((gc ^ sl) & 7);
        s16x8 kf = *(const s16x8*)(Kl[cur] + sl*128 + cl*8);
        sacc[stile] = __builtin_amdgcn_mfma_f32_32x32x16_bf16(kf, qf[kc], sacc[stile], 0,0,0);
      }
    }

    float tm[8];
    #pragma unroll
    for (int i=0;i<8;++i)
      tm[i] = fmaxf(fmaxf(sacc[0][i], sacc[0][i+8]), fmaxf(sacc[1][i], sacc[1][i+8]));
    float pm = fmaxf(fmaxf(fmaxf(tm[0],tm[1]), fmaxf(tm[2],tm[3])),
                     fmaxf(fmaxf(tm[4],tm[5]), fmaxf(tm[6],tm[7])));
    pm = fmaxf(pm, __shfl_xor(pm, 32));

    if (__any(pm > m_run + 8.f)) {
      const float mnew = fmaxf(m_run, pm);
      const float alpha = __expf(m_run - mnew);
      m_run = mnew;
      l_run *= alpha;
      #pragma unroll
      for (int r=0;r<16;++r) {
        const int qr = (r&3) + 8*(r>>2) + 4*hi;
        const float ar = __shfl(alpha, qr);
        #pragma unroll
        for (int dt2=0;dt2<4;++dt2) oacc[dt2][r] *= ar;
      }
    }

    float ps = 0.f;
    #pragma unroll
    for (int stile=0; stile<2; ++stile)
      #pragma unroll
      for (int i=0;i<16;++i) {
        const float v = __expf(sacc[stile][i] - m_run);
        sacc[stile][i] = v;
        ps += v;
      }
    ps += __shfl_xor(ps, 32);
    l_run += ps;

    s16x8 pf[4];
    #pragma unroll
    for (int kc2=0; kc2<4; ++kc2) {
      const int stile = kc2 >> 1;
      const int rb = (kc2 & 1) * 8;
      const unsigned A = cvt_pk_bf16(sacc[stile][rb+0], sacc[stile][rb+1]);
      const unsigned B = cvt_pk_bf16(sacc[stile][rb+2], sacc[stile][rb+3]);
      const unsigned C = cvt_pk_bf16(sacc[stile][rb+4], sacc[stile][rb+5]);
      const unsigned D = cvt_pk_bf16(sacc[stile][rb+6], sacc[stile][rb+7]);
      const unsigned x1 = (unsigned)__shfl_xor((int)(hi ? A : C), 32);
      const unsigned x2 = (unsigned)__shfl_xor((int)(hi ? B : D), 32);
      union { unsigned u[4]; s16x8 v; } fr;
      fr.u[0] = hi ? x1 : A;
      fr.u[1] = hi ? x2 : B;
      fr.u[2] = hi ? C : x1;
      fr.u[3] = hi ? D : x2;
      pf[kc2] = fr.v;
    }

    #pragma unroll
    for (int dt2=0; dt2<4; ++dt2) {
      const int d = dt2*32 + l31;
      #pragma unroll
      for (int kc2=0; kc2<4; ++kc2) {
        const int g3 = kc2*2 + hi;
        const int cl3 = (g3 ^ d) & 7;
        s16x8 vf = *(const s16x8*)(Vl[cur] + d*64 + cl3*8);
        oacc[dt2] = __builtin_amdgcn_mfma_f32_32x32x16_bf16(pf[kc2], vf, oacc[dt2], 0,0,0);
      }
    }

    __syncthreads();
    cur ^= 1;
  }

  const float linv = 1.f / l_run;
  #pragma unroll
  for (int r=0;r<16;++r) {
    const int qr = (r&3) + 8*(r>>2) + 4*hi;
    const float lr = __shfl(linv, qr);
    const size_t row = (size_t)(b*1024 + q0 + qr)*1024 + colh;
    #pragma unroll
    for (int dt2=0;dt2<4;++dt2)
      O[row + dt2*32 + l31] = f2bf(oacc[dt2][r] * lr);
  }
}

// ---------------- LayerNorm (block per row of 1024) ----------------

__global__ __launch_bounds__(256) void ln_kernel(
    const float* __restrict__ y, const float* __restrict__ g, const float* __restrict__ bb,
    u16* __restrict__ out)
{
  const int row = blockIdx.x, t = threadIdx.x;
  float4 v = ((const float4*)y)[row*256 + t];
  float s  = v.x + v.y + v.z + v.w;
  float s2 = v.x*v.x + v.y*v.y + v.z*v.z + v.w*v.w;
  #pragma unroll
  for (int off=1; off<64; off<<=1) { s += __shfl_xor(s, off); s2 += __shfl_xor(s2, off); }
  __shared__ float ps[4], ps2[4];
  const int w = t >> 6;
  if ((t & 63) == 0) { ps[w] = s; ps2[w] = s2; }
  __syncthreads();
  s  = ps[0] + ps[1] + ps[2] + ps[3];
  s2 = ps2[0] + ps2[1] + ps2[2] + ps2[3];
  const float mu = s * (1.f/1024.f);
  const float var = s2 * (1.f/1024.f) - mu*mu;
  const float rs = rsqrtf(var + 1e-5f);
  float4 gg = ((const float4*)g)[t];
  float4 bv = ((const float4*)bb)[t];
  u16x4 o = { f2bf((v.x-mu)*rs*gg.x + bv.x),
              f2bf((v.y-mu)*rs*gg.y + bv.y),
              f2bf((v.z-mu)*rs*gg.z + bv.z),
              f2bf((v.w-mu)*rs*gg.w + bv.w) };
  ((u16x4*)out)[row*256 + t] = o;
}

// ---------------- launcher ----------------

extern "C" void kernel_launch(void* const* d_in, const int* in_sizes, int n_in,
                              void* d_out, int out_size, void* d_ws, size_t ws_size,
                              hipStream_t stream)
{
  (void)in_sizes; (void)n_in; (void)out_size; (void)ws_size;
  const float* x   = (const float*)d_in[0];
  const float* ht  = (const float*)d_in[1];
  const float* ha  = (const float*)d_in[2];
  const float* pp  = (const float*)d_in[3];
  const float* Wq  = (const float*)d_in[4];
  const float* bq  = (const float*)d_in[5];
  const float* Wk  = (const float*)d_in[6];
  const float* bk  = (const float*)d_in[7];
  const float* Wv  = (const float*)d_in[8];
  const float* bv  = (const float*)d_in[9];
  const float* Wo  = (const float*)d_in[10];
  const float* bo  = (const float*)d_in[11];
  const float* gat = (const float*)d_in[12];
  const float* lng = (const float*)d_in[13];
  const float* lnb = (const float*)d_in[14];
  const float* Wf  = (const float*)d_in[15];
  const float* bfp = (const float*)d_in[16];
  float* out = (float*)d_out;

  char* ws = (char*)d_ws;
  size_t off = 0;
  auto alloc = [&](size_t bytes) { void* r = ws + off; off += (bytes + 255) & ~255ull; return r; };
  u16* M    = (u16*)alloc(13312ull*1024*2);  // dead after QKV gemm; Vtg/Y overlay
  u16* Wqkv = (u16*)alloc(3072ull*1024*2);   // dead after QKV gemm
  u16* Wobf = (u16*)alloc(1024ull*1024*2);
  u16* Wfbf = (u16*)alloc(1024ull*1024*2);
  u16* Qb   = (u16*)alloc(8192ull*1024*2);   // dead after flash
  u16* Kb2  = (u16*)alloc(13312ull*1024*2);
  u16* Vb2  = (u16*)alloc(13312ull*1024*2);
  u16* Ab   = (u16*)alloc(8192ull*1024*2);
  u16* Vtg  = M;                             // V^T overlay on M
  float* Y  = (float*)M;                     // fp32 y overlays M+Wqkv after flash
  u16* Ln   = Qb;

  hipLaunchKernelGGL(cvt_weights, dim3(5120), dim3(256), 0, stream,
                     Wq, Wk, Wv, Wo, Wf, Wqkv, Wobf, Wfbf);
  hipLaunchKernelGGL(build_m, dim3(13312), dim3(256), 0, stream, x, ht, ha, pp, M);
  hipLaunchKernelGGL(gemm256_qkv, dim3(624), dim3(512), 0, stream,
                     M, Wqkv, bq, bk, bv, gat, Qb, Kb2, Vb2);
  hipLaunchKernelGGL(vtrans, dim3(26, 16, 8), dim3(256), 0, stream, Vb2, Vtg);
  hipLaunchKernelGGL(flash_attn, dim3(512), dim3(256), 0, stream, Qb, Kb2, Vtg, Ab);
  hipLaunchKernelGGL((gemm_bt<1>), dim3(64, 8), dim3(256), 0, stream,
                     Ab, Wobf, 1024, bo, (const void*)x, (void*)Y);
  hipLaunchKernelGGL(ln_kernel, dim3(8192), dim3(256), 0, stream, Y, lng, lnb, Ln);
  hipLaunchKernelGGL((gemm_bt<2>), dim3(64, 8), dim3(256), 0, stream,
                     Ln, Wfbf, 1024, bfp, nullptr, (void*)out);
}

// Round 7
// 425.902 us; speedup vs baseline: 1.3888x; 1.1167x over previous
//
#include <hip/hip_runtime.h>
#include <hip/hip_bf16.h>
#include <math.h>

typedef unsigned short u16;
typedef __attribute__((ext_vector_type(8))) short s16x8;
typedef __attribute__((ext_vector_type(4))) float f32x4;
typedef __attribute__((ext_vector_type(16))) float f32x16;
typedef __attribute__((ext_vector_type(4))) unsigned short u16x4;

__device__ __forceinline__ u16 f2bf(float f) {
  union { float f; unsigned u; } v; v.f = f;
  unsigned r = (v.u + 0x7FFFu + ((v.u >> 16) & 1u)) >> 16;
  return (u16)r;
}

__device__ __forceinline__ void gload16(const void* g, void* l) {
  __builtin_amdgcn_global_load_lds((const __attribute__((address_space(1))) unsigned int*)g,
                                   (__attribute__((address_space(3))) unsigned int*)l, 16, 0, 0);
}

__device__ __forceinline__ unsigned cvt_pk_bf16(float a, float b) {
  unsigned r;
  asm("v_cvt_pk_bf16_f32 %0, %1, %2" : "=v"(r) : "v"(a), "v"(b));
  return r;
}

// ---------------- elementwise prep ----------------

__global__ __launch_bounds__(256) void cvt_weights(
    const float* __restrict__ wq, const float* __restrict__ wk, const float* __restrict__ wv,
    const float* __restrict__ wo, const float* __restrict__ wf,
    u16* __restrict__ wqkv, u16* __restrict__ wobf, u16* __restrict__ wfbf)
{
  int i = blockIdx.x * 256 + threadIdx.x;   // 5 * 262144 float4 units
  int which = i >> 18;
  int idx = i & 262143;
  const float* src = which==0 ? wq : which==1 ? wk : which==2 ? wv : which==3 ? wo : wf;
  float4 v = ((const float4*)src)[idx];
  u16x4 o = { f2bf(v.x), f2bf(v.y), f2bf(v.z), f2bf(v.w) };
  u16* dst = which < 3 ? (wqkv + (size_t)which*1048576) : (which==3 ? wobf : wfbf);
  ((u16x4*)dst)[idx] = o;
}

// M[b*1664 + s] = rows of [x(1024); h_a(64); p(64); h_t(512)] per batch, bf16
__global__ __launch_bounds__(256) void build_m(
    const float* __restrict__ x, const float* __restrict__ ht,
    const float* __restrict__ ha, const float* __restrict__ p,
    u16* __restrict__ M)
{
  int row = blockIdx.x; int t = threadIdx.x;
  int b = row / 1664, s = row % 1664;
  const float* src;
  if (s < 1024)      src = x  + (size_t)(b*1024 + s)*1024;
  else if (s < 1088) src = ha + (size_t)(b*64 + (s-1024))*1024;
  else if (s < 1152) src = p  + (size_t)(b*64 + (s-1088))*1024;
  else               src = ht + (size_t)(b*512 + (s-1152))*1024;
  float4 v = ((const float4*)src)[t];
  u16x4 o = { f2bf(v.x), f2bf(v.y), f2bf(v.z), f2bf(v.w) };
  ((u16x4*)(M + (size_t)row*1024))[t] = o;
}

// ---------------- 128x128 QKV GEMM: BK=32, triple-buffered, 3 blocks/CU ----------------
// C[13312,3072] = M[13312,1024] @ Wqkv[3072,1024]^T, fused QKV epilogue.
// Per K-tile: 4 gload16 (depth-2 prefetch) + 8 ds_read_b128 + 16 MFMA +
// ONE fused {vmcnt(4), s_barrier}. Counted vmcnt: never 0 until tail.

__global__ __launch_bounds__(256, 3) void gemm128_qkv(
    const u16* __restrict__ A, const u16* __restrict__ Bw,
    const float* __restrict__ bias_q, const float* __restrict__ bias_k,
    const float* __restrict__ bias_v, const float* __restrict__ gat,
    u16* __restrict__ Qb, u16* __restrict__ Kb, u16* __restrict__ Vb)
{
  __shared__ __align__(16) u16 As3[3][128*32];   // 8 KB per buf per matrix
  __shared__ __align__(16) u16 Bs3[3][128*32];   // total LDS = 48 KB -> 3 blocks/CU

  const int tid = threadIdx.x;
  const int l = tid & 63;
  const int w = tid >> 6;            // 0..3
  const int wr = w >> 1, wc = w & 1; // 2x2 wave grid, 64x64 per wave
  const int l15 = l & 15, lg = l >> 4;

  // XCD-chunked swizzle: 2496 blocks = 8 x 312. Each XCD owns 13 contiguous mt
  // (A slice 3.25 MB, L2-resident) x nt-groups of 4 (B working set 1 MB).
  const int b0 = blockIdx.x;
  const int xcd = b0 & 7;
  const int loc = b0 >> 3;           // 0..311
  const int g = loc / 52, r5 = loc % 52;
  const int mt = xcd*13 + (r5 % 13);
  const int nt = g*4 + (r5 / 13);
  const int m0 = mt * 128, n0 = nt * 128;

  if (n0 < 1024 && (m0 % 1664) >= 1024) return;  // Q-only tile, all non-token rows

  // stage K-tile kt into buffer sb: 2 gload16 per matrix per thread.
  // chunk-XOR swizzle c^=(r>>1)&3 applied via pre-swizzled GLOBAL source.
  auto stage = [&](int kt, int sb) {
    #pragma unroll
    for (int i=0;i<2;++i) {
      const int e = i*256 + tid;
      const int rr = e >> 2, c2 = e & 3;
      const int gch = c2 ^ ((rr >> 1) & 3);
      gload16(A + (size_t)(m0 + rr)*1024 + kt*32 + gch*8,
              (void*)(As3[sb] + (i*256 + w*64)*8));
    }
    #pragma unroll
    for (int i=0;i<2;++i) {
      const int e = i*256 + tid;
      const int rr = e >> 2, c2 = e & 3;
      const int gch = c2 ^ ((rr >> 1) & 3);
      gload16(Bw + (size_t)(n0 + rr)*1024 + kt*32 + gch*8,
              (void*)(Bs3[sb] + (i*256 + w*64)*8));
    }
  };

  f32x4 acc[4][4];
  #pragma unroll
  for (int i=0;i<4;++i)
    #pragma unroll
    for (int j=0;j<4;++j) acc[i][j] = (f32x4){0,0,0,0};

  // prologue: tiles 0,1 staged; wait tile0 (retire oldest 4 of 8)
  stage(0, 0); stage(1, 1);
  asm volatile("s_waitcnt vmcnt(4)\ns_barrier" ::: "memory");

  int cur = 0;
  for (int t = 0; t < 32; ++t) {
    const int sb = cur >= 1 ? cur - 1 : 2;   // (cur+2)%3 == buffer freed at t-1
    if (t + 2 < 32) stage(t + 2, sb);

    s16x8 af[4], bf[4];
    #pragma unroll
    for (int mi=0;mi<4;++mi) {
      const int rr = wr*64 + mi*16 + l15;
      af[mi] = *(const s16x8*)(As3[cur] + rr*32 + ((lg ^ ((rr>>1)&3))<<3));
    }
    #pragma unroll
    for (int ni=0;ni<4;++ni) {
      const int rr = wc*64 + ni*16 + l15;
      bf[ni] = *(const s16x8*)(Bs3[cur] + rr*32 + ((lg ^ ((rr>>1)&3))<<3));
    }

    __builtin_amdgcn_s_setprio(1);
    #pragma unroll
    for (int mi=0;mi<4;++mi)
      #pragma unroll
      for (int ni=0;ni<4;++ni)
        acc[mi][ni] = __builtin_amdgcn_mfma_f32_16x16x32_bf16(af[mi], bf[ni], acc[mi][ni], 0,0,0);
    __builtin_amdgcn_s_setprio(0);

    // end-of-iter: next tile must be resident; all waves done reading cur
    // (cur's slot is restaged at t+1). outstanding = (t+1):4 + (t+2):4.
    if (t < 30)       asm volatile("s_waitcnt vmcnt(4)\ns_barrier" ::: "memory");
    else if (t == 30) asm volatile("s_waitcnt vmcnt(0)\ns_barrier" ::: "memory");
    cur = cur == 2 ? 0 : cur + 1;
  }

  // epilogue: fused QKV write
  const float ratio = tanhf(gat[0]);
  #pragma unroll
  for (int mi=0;mi<4;++mi) {
    #pragma unroll
    for (int ni=0;ni<4;++ni) {
      #pragma unroll
      for (int rr=0;rr<4;++rr) {
        const int row = m0 + wr*64 + mi*16 + lg*4 + rr;
        const int col = n0 + wc*64 + ni*16 + l15;
        const int b = row / 1664, s = row % 1664;
        const float a = acc[mi][ni][rr];
        if (col < 1024) {
          if (s < 1024) {
            float v = a + bias_q[col];
            Qb[(size_t)(b*1024 + s)*1024 + col] = f2bf(v * 0.08838834764831845f);
          }
        } else if (col < 2048) {
          float v = a + bias_k[col-1024];
          if (s >= 1152) v *= ratio;
          Kb[(size_t)row*1024 + (col-1024)] = f2bf(v);
        } else {
          float v = a + bias_v[col-2048];
          Vb[(size_t)row*1024 + (col-2048)] = f2bf(v);
        }
      }
    }
  }
}

// ---------------- GEMM: C[M,N] = A[M,K] @ B[N,K]^T, m97-style 128x128 tile ----------------
// EPI 1: +bo +x -> fp32 y. EPI 2: +bf, relu -> fp32 out.

template<int EPI>
__global__ __launch_bounds__(256) void gemm_bt(
    const u16* __restrict__ A, const u16* __restrict__ Bw, int K,
    const float* __restrict__ bias0,
    const void* p0, void* p1)
{
  __shared__ __align__(16) u16 As[128*32];
  __shared__ __align__(16) u16 Bs[128*32];
  const int tid = threadIdx.x;
  const int l = tid & 63;
  const int w = tid >> 6;
  const int m0 = blockIdx.x * 128;
  const int n0 = blockIdx.y * 128;

  const int wr = w >> 1, wc = w & 1;
  const int l15 = l & 15, lg = l >> 4;

  f32x4 acc[4][4];
  #pragma unroll
  for (int i=0;i<4;++i)
    #pragma unroll
    for (int j=0;j<4;++j) acc[i][j] = (f32x4){0,0,0,0};

  const int kiters = K >> 5;
  for (int kt = 0; kt < kiters; ++kt) {
    __syncthreads();
    #pragma unroll
    for (int c = 0; c < 2; ++c) {
      const int rbase = w*32 + c*16;
      const int rl = rbase + (l >> 2);
      const int kb = kt*32 + (l & 3)*8;
      gload16(A  + (size_t)(m0 + rl)*K + kb, (void*)(As + rbase*32));
      gload16(Bw + (size_t)(n0 + rl)*K + kb, (void*)(Bs + rbase*32));
    }
    __syncthreads();
    s16x8 av[4];
    #pragma unroll
    for (int mi=0;mi<4;++mi)
      av[mi] = *(const s16x8*)(As + (wr*64 + mi*16 + l15)*32 + lg*8);
    #pragma unroll
    for (int ni=0;ni<4;++ni) {
      s16x8 bv = *(const s16x8*)(Bs + (wc*64 + ni*16 + l15)*32 + lg*8);
      #pragma unroll
      for (int mi=0;mi<4;++mi)
        acc[mi][ni] = __builtin_amdgcn_mfma_f32_16x16x32_bf16(av[mi], bv, acc[mi][ni], 0,0,0);
    }
  }

  #pragma unroll
  for (int mi=0;mi<4;++mi) {
    #pragma unroll
    for (int ni=0;ni<4;++ni) {
      #pragma unroll
      for (int r=0;r<4;++r) {
        const int row = m0 + wr*64 + mi*16 + lg*4 + r;
        const int col = n0 + wc*64 + ni*16 + l15;
        if constexpr (EPI == 1) {
          float v = acc[mi][ni][r] + bias0[col] + ((const float*)p0)[(size_t)row*1024 + col];
          ((float*)p1)[(size_t)row*1024 + col] = v;
        } else {
          float v = acc[mi][ni][r] + bias0[col];
          ((float*)p1)[(size_t)row*1024 + col] = fmaxf(v, 0.f);
        }
      }
    }
  }
}

// ---------------- V transpose: Vt[b][c=1024][s=1664] = V[b][s][c] ----------------

__global__ __launch_bounds__(256) void vtrans(
    const u16* __restrict__ V, u16* __restrict__ Vt)
{
  __shared__ u16 Ls[64][68];
  const int st = blockIdx.x, dt = blockIdx.y, b = blockIdx.z;
  const int t = threadIdx.x;
  const int rq = t >> 4, c4 = t & 15;
  #pragma unroll
  for (int i=0;i<4;++i) {
    const int r = i*16 + rq;
    u16x4 v = *(const u16x4*)(V + ((size_t)(b*1664 + st*64 + r))*1024 + dt*64 + c4*4);
    Ls[r][c4*4+0] = v[0]; Ls[r][c4*4+1] = v[1]; Ls[r][c4*4+2] = v[2]; Ls[r][c4*4+3] = v[3];
  }
  __syncthreads();
  #pragma unroll
  for (int i=0;i<4;++i) {
    const int dr = i*16 + rq;
    u16x4 ov = { Ls[c4*4+0][dr], Ls[c4*4+1][dr], Ls[c4*4+2][dr], Ls[c4*4+3][dr] };
    *(u16x4*)(Vt + ((size_t)(b*1024 + dt*64 + dr))*1664 + st*64 + c4*4) = ov;
  }
}

// ---------------- flash attention, 32x32 swapped-QK, S=1664, D=128 ----------------

__global__ __launch_bounds__(256, 2) void flash_attn(
    const u16* __restrict__ Q, const u16* __restrict__ Kb, const u16* __restrict__ Vtg,
    u16* __restrict__ O)
{
  __shared__ __align__(16) u16 Kl[2][64*128];   // [s][16 chunks], chunk low3 ^= s&7
  __shared__ __align__(16) u16 Vl[2][128*64];   // [d][8 chunks], chunk ^= d&7

  const int tid = threadIdx.x;
  const int l = tid & 63;
  const int w = tid >> 6;
  const int l31 = l & 31;
  const int hi = l >> 5;
  const int bh = blockIdx.x & 63;
  const int qt = blockIdx.x >> 6;
  const int b = bh >> 3, h = bh & 7;
  const int colh = h * 128;
  const int q0 = qt*128 + w*32;

  s16x8 qf[8];
  {
    const size_t qrow = (size_t)(b*1024 + q0 + l31)*1024 + colh;
    #pragma unroll
    for (int kc=0;kc<8;++kc)
      qf[kc] = *(const s16x8*)(Q + qrow + kc*16 + hi*8);
  }

  f32x16 oacc[4];
  #pragma unroll
  for (int dt2=0;dt2<4;++dt2)
    #pragma unroll
    for (int i=0;i<16;++i) oacc[dt2][i] = 0.f;
  float m_run = -INFINITY, l_run = 0.f;

  const size_t kbase  = (size_t)(b*1664)*1024 + colh;
  const size_t vtbase = (size_t)(b*1024 + colh)*1664;

  auto stage = [&](int st, int nb) {
    const int s0 = st*64;
    #pragma unroll
    for (int i=0;i<4;++i) {
      const int e = i*256 + tid;
      const int sl = e >> 4, c = e & 15;
      const int g = (c & 8) | ((c ^ sl) & 7);
      gload16(Kb + kbase + (size_t)(s0 + sl)*1024 + g*8,
              (void*)(Kl[nb] + (i*256 + w*64)*8));
    }
    #pragma unroll
    for (int i=0;i<4;++i) {
      const int e = i*256 + tid;
      const int d = e >> 3, c3 = e & 7;
      const int g3 = (c3 ^ d) & 7;
      gload16(Vtg + vtbase + (size_t)d*1664 + s0 + g3*8,
              (void*)(Vl[nb] + (i*256 + w*64)*8));
    }
  };

  stage(0, 0);
  __syncthreads();
  int cur = 0;

  for (int st=0; st<26; ++st) {
    if (st + 1 < 26) stage(st + 1, cur ^ 1);

    f32x16 sacc[2];
    #pragma unroll
    for (int stile=0; stile<2; ++stile) {
      #pragma unroll
      for (int i=0;i<16;++i) sacc[stile][i] = 0.f;
      #pragma unroll
      for (int kc=0; kc<8; ++kc) {
        const int sl = stile*32 + l31;
        const int gc = kc*2 + hi;
        const int cl = (gc & 8) | ((gc ^ sl) & 7);
        s16x8 kf = *(const s16x8*)(Kl[cur] + sl*128 + cl*8);
        sacc[stile] = __builtin_amdgcn_mfma_f32_32x32x16_bf16(kf, qf[kc], sacc[stile], 0,0,0);
      }
    }

    float tm[8];
    #pragma unroll
    for (int i=0;i<8;++i)
      tm[i] = fmaxf(fmaxf(sacc[0][i], sacc[0][i+8]), fmaxf(sacc[1][i], sacc[1][i+8]));
    float pm = fmaxf(fmaxf(fmaxf(tm[0],tm[1]), fmaxf(tm[2],tm[3])),
                     fmaxf(fmaxf(tm[4],tm[5]), fmaxf(tm[6],tm[7])));
    pm = fmaxf(pm, __shfl_xor(pm, 32));

    if (__any(pm > m_run + 8.f)) {
      const float mnew = fmaxf(m_run, pm);
      const float alpha = __expf(m_run - mnew);
      m_run = mnew;
      l_run *= alpha;
      #pragma unroll
      for (int r=0;r<16;++r) {
        const int qr = (r&3) + 8*(r>>2) + 4*hi;
        const float ar = __shfl(alpha, qr);
        #pragma unroll
        for (int dt2=0;dt2<4;++dt2) oacc[dt2][r] *= ar;
      }
    }

    float ps = 0.f;
    #pragma unroll
    for (int stile=0; stile<2; ++stile)
      #pragma unroll
      for (int i=0;i<16;++i) {
        const float v = __expf(sacc[stile][i] - m_run);
        sacc[stile][i] = v;
        ps += v;
      }
    ps += __shfl_xor(ps, 32);
    l_run += ps;

    s16x8 pf[4];
    #pragma unroll
    for (int kc2=0; kc2<4; ++kc2) {
      const int stile = kc2 >> 1;
      const int rb = (kc2 & 1) * 8;
      const unsigned A = cvt_pk_bf16(sacc[stile][rb+0], sacc[stile][rb+1]);
      const unsigned B = cvt_pk_bf16(sacc[stile][rb+2], sacc[stile][rb+3]);
      const unsigned C = cvt_pk_bf16(sacc[stile][rb+4], sacc[stile][rb+5]);
      const unsigned D = cvt_pk_bf16(sacc[stile][rb+6], sacc[stile][rb+7]);
      const unsigned x1 = (unsigned)__shfl_xor((int)(hi ? A : C), 32);
      const unsigned x2 = (unsigned)__shfl_xor((int)(hi ? B : D), 32);
      union { unsigned u[4]; s16x8 v; } fr;
      fr.u[0] = hi ? x1 : A;
      fr.u[1] = hi ? x2 : B;
      fr.u[2] = hi ? C : x1;
      fr.u[3] = hi ? D : x2;
      pf[kc2] = fr.v;
    }

    #pragma unroll
    for (int dt2=0; dt2<4; ++dt2) {
      const int d = dt2*32 + l31;
      #pragma unroll
      for (int kc2=0; kc2<4; ++kc2) {
        const int g3 = kc2*2 + hi;
        const int cl3 = (g3 ^ d) & 7;
        s16x8 vf = *(const s16x8*)(Vl[cur] + d*64 + cl3*8);
        oacc[dt2] = __builtin_amdgcn_mfma_f32_32x32x16_bf16(pf[kc2], vf, oacc[dt2], 0,0,0);
      }
    }

    __syncthreads();
    cur ^= 1;
  }

  const float linv = 1.f / l_run;
  #pragma unroll
  for (int r=0;r<16;++r) {
    const int qr = (r&3) + 8*(r>>2) + 4*hi;
    const float lr = __shfl(linv, qr);
    const size_t row = (size_t)(b*1024 + q0 + qr)*1024 + colh;
    #pragma unroll
    for (int dt2=0;dt2<4;++dt2)
      O[row + dt2*32 + l31] = f2bf(oacc[dt2][r] * lr);
  }
}

// ---------------- LayerNorm (block per row of 1024) ----------------

__global__ __launch_bounds__(256) void ln_kernel(
    const float* __restrict__ y, const float* __restrict__ g, const float* __restrict__ bb,
    u16* __restrict__ out)
{
  const int row = blockIdx.x, t = threadIdx.x;
  float4 v = ((const float4*)y)[row*256 + t];
  float s  = v.x + v.y + v.z + v.w;
  float s2 = v.x*v.x + v.y*v.y + v.z*v.z + v.w*v.w;
  #pragma unroll
  for (int off=1; off<64; off<<=1) { s += __shfl_xor(s, off); s2 += __shfl_xor(s2, off); }
  __shared__ float ps[4], ps2[4];
  const int w = t >> 6;
  if ((t & 63) == 0) { ps[w] = s; ps2[w] = s2; }
  __syncthreads();
  s  = ps[0] + ps[1] + ps[2] + ps[3];
  s2 = ps2[0] + ps2[1] + ps2[2] + ps2[3];
  const float mu = s * (1.f/1024.f);
  const float var = s2 * (1.f/1024.f) - mu*mu;
  const float rs = rsqrtf(var + 1e-5f);
  float4 gg = ((const float4*)g)[t];
  float4 bv = ((const float4*)bb)[t];
  u16x4 o = { f2bf((v.x-mu)*rs*gg.x + bv.x),
              f2bf((v.y-mu)*rs*gg.y + bv.y),
              f2bf((v.z-mu)*rs*gg.z + bv.z),
              f2bf((v.w-mu)*rs*gg.w + bv.w) };
  ((u16x4*)out)[row*256 + t] = o;
}

// ---------------- launcher ----------------

extern "C" void kernel_launch(void* const* d_in, const int* in_sizes, int n_in,
                              void* d_out, int out_size, void* d_ws, size_t ws_size,
                              hipStream_t stream)
{
  (void)in_sizes; (void)n_in; (void)out_size; (void)ws_size;
  const float* x   = (const float*)d_in[0];
  const float* ht  = (const float*)d_in[1];
  const float* ha  = (const float*)d_in[2];
  const float* pp  = (const float*)d_in[3];
  const float* Wq  = (const float*)d_in[4];
  const float* bq  = (const float*)d_in[5];
  const float* Wk  = (const float*)d_in[6];
  const float* bk  = (const float*)d_in[7];
  const float* Wv  = (const float*)d_in[8];
  const float* bv  = (const float*)d_in[9];
  const float* Wo  = (const float*)d_in[10];
  const float* bo  = (const float*)d_in[11];
  const float* gat = (const float*)d_in[12];
  const float* lng = (const float*)d_in[13];
  const float* lnb = (const float*)d_in[14];
  const float* Wf  = (const float*)d_in[15];
  const float* bfp = (const float*)d_in[16];
  float* out = (float*)d_out;

  char* ws = (char*)d_ws;
  size_t off = 0;
  auto alloc = [&](size_t bytes) { void* r = ws + off; off += (bytes + 255) & ~255ull; return r; };
  u16* M    = (u16*)alloc(13312ull*1024*2);  // dead after QKV gemm; Vtg/Y overlay
  u16* Wqkv = (u16*)alloc(3072ull*1024*2);   // dead after QKV gemm
  u16* Wobf = (u16*)alloc(1024ull*1024*2);
  u16* Wfbf = (u16*)alloc(1024ull*1024*2);
  u16* Qb   = (u16*)alloc(8192ull*1024*2);   // dead after flash
  u16* Kb2  = (u16*)alloc(13312ull*1024*2);
  u16* Vb2  = (u16*)alloc(13312ull*1024*2);
  u16* Ab   = (u16*)alloc(8192ull*1024*2);
  u16* Vtg  = M;                             // V^T overlay on M
  float* Y  = (float*)M;                     // fp32 y overlays M+Wqkv after flash
  u16* Ln   = Qb;

  hipLaunchKernelGGL(cvt_weights, dim3(5120), dim3(256), 0, stream,
                     Wq, Wk, Wv, Wo, Wf, Wqkv, Wobf, Wfbf);
  hipLaunchKernelGGL(build_m, dim3(13312), dim3(256), 0, stream, x, ht, ha, pp, M);
  hipLaunchKernelGGL(gemm128_qkv, dim3(2496), dim3(256), 0, stream,
                     M, Wqkv, bq, bk, bv, gat, Qb, Kb2, Vb2);
  hipLaunchKernelGGL(vtrans, dim3(26, 16, 8), dim3(256), 0, stream, Vb2, Vtg);
  hipLaunchKernelGGL(flash_attn, dim3(512), dim3(256), 0, stream, Qb, Kb2, Vtg, Ab);
  hipLaunchKernelGGL((gemm_bt<1>), dim3(64, 8), dim3(256), 0, stream,
                     Ab, Wobf, 1024, bo, (const void*)x, (void*)Y);
  hipLaunchKernelGGL(ln_kernel, dim3(8192), dim3(256), 0, stream, Y, lng, lnb, Ln);
  hipLaunchKernelGGL((gemm_bt<2>), dim3(64, 8), dim3(256), 0, stream,
                     Ln, Wfbf, 1024, bfp, nullptr, (void*)out);
}